// Round 1
// baseline (3049.614 us; speedup 1.0000x reference)
//
#include <hip/hip_runtime.h>
#include <hip/hip_bf16.h>

#define D_MODEL 1024
#define D_STATE 16
#define D_CONV  4
#define D_INNER 2048
#define BATCH   2
#define SEQ     2048
#define NTOK    (BATCH * SEQ)      // 4096
#define NXZ     (2 * D_INNER)      // 4096
#define NDBL    (2 * D_STATE + 1)  // 33

__device__ __forceinline__ float silu_f(float x) { return x / (1.0f + expf(-x)); }

// ---------------------------------------------------------------------------
// C[M,N] = A[M,K] * B[N,K]^T   (both row-major; M,N multiples of 64, K of 16)
// BM=BN=64, BK=16, 256 threads, 4x4 per thread.
// ---------------------------------------------------------------------------
__launch_bounds__(256)
__global__ void sgemm_nt(const float* __restrict__ A, const float* __restrict__ B,
                         float* __restrict__ C, int M, int N, int K)
{
    constexpr int BM = 64, BN = 64, BK = 16, TM = 4, TN = 4;
    __shared__ float As[BK][BM + 1];
    __shared__ float Bs[BK][BN + 1];

    const int tid = threadIdx.x;
    const int tx = tid % (BN / TN);   // 0..15 (N dir)
    const int ty = tid / (BN / TN);   // 0..15 (M dir)
    const int bn = blockIdx.x, bm = blockIdx.y;

    const float* Ab = A + (size_t)bm * BM * K;
    const float* Bb = B + (size_t)bn * BN * K;

    const int lrow = tid >> 2;   // 0..63
    const int lseg = tid & 3;    // 0..3  (float4 segment within BK=16)

    float acc[TM][TN] = {};

    for (int k0 = 0; k0 < K; k0 += BK) {
        float4 av = *(const float4*)(Ab + (size_t)lrow * K + k0 + lseg * 4);
        float4 bv = *(const float4*)(Bb + (size_t)lrow * K + k0 + lseg * 4);
        As[lseg * 4 + 0][lrow] = av.x; As[lseg * 4 + 1][lrow] = av.y;
        As[lseg * 4 + 2][lrow] = av.z; As[lseg * 4 + 3][lrow] = av.w;
        Bs[lseg * 4 + 0][lrow] = bv.x; Bs[lseg * 4 + 1][lrow] = bv.y;
        Bs[lseg * 4 + 2][lrow] = bv.z; Bs[lseg * 4 + 3][lrow] = bv.w;
        __syncthreads();

#pragma unroll
        for (int k = 0; k < BK; ++k) {
            float am[TM], bnv[TN];
#pragma unroll
            for (int i = 0; i < TM; ++i) am[i] = As[k][ty * TM + i];
#pragma unroll
            for (int j = 0; j < TN; ++j) bnv[j] = Bs[k][tx * TN + j];
#pragma unroll
            for (int i = 0; i < TM; ++i)
#pragma unroll
                for (int j = 0; j < TN; ++j)
                    acc[i][j] = fmaf(am[i], bnv[j], acc[i][j]);
        }
        __syncthreads();
    }

#pragma unroll
    for (int i = 0; i < TM; ++i) {
        float4 o = make_float4(acc[i][0], acc[i][1], acc[i][2], acc[i][3]);
        *(float4*)(C + (size_t)(bm * BM + ty * TM + i) * N + bn * BN + tx * TN) = o;
    }
}

// ---------------------------------------------------------------------------
// Depthwise causal conv (k=4) + bias + SiLU.  Input: first half of xz rows.
// xz row stride = NXZ.  Output xi[t, d] (row stride D_INNER).
// ---------------------------------------------------------------------------
__global__ void conv_silu_kernel(const float* __restrict__ xz,
                                 const float* __restrict__ conv_w,
                                 const float* __restrict__ conv_b,
                                 float* __restrict__ xi)
{
    int idx = blockIdx.x * blockDim.x + threadIdx.x;
    if (idx >= NTOK * D_INNER) return;
    int d = idx % D_INNER;
    int t = idx / D_INNER;
    int l = t % SEQ;
    int b = t / SEQ;

    float w0 = conv_w[d * 4 + 0], w1 = conv_w[d * 4 + 1];
    float w2 = conv_w[d * 4 + 2], w3 = conv_w[d * 4 + 3];

    const float* base = xz + ((size_t)b * SEQ) * NXZ + d;  // channel-d column
    float acc = conv_b[d];
    if (l >= 3) acc = fmaf(w0, base[(size_t)(l - 3) * NXZ], acc);
    if (l >= 2) acc = fmaf(w1, base[(size_t)(l - 2) * NXZ], acc);
    if (l >= 1) acc = fmaf(w2, base[(size_t)(l - 1) * NXZ], acc);
    acc = fmaf(w3, base[(size_t)l * NXZ], acc);
    xi[idx] = silu_f(acc);
}

// ---------------------------------------------------------------------------
// x_dbl[t, e] = sum_d xi[t,d] * W_x[e,d],  e in [0,33).  Block per token.
// ---------------------------------------------------------------------------
__launch_bounds__(256)
__global__ void xdbl_kernel(const float* __restrict__ xi,
                            const float* __restrict__ W_x,
                            float* __restrict__ xdbl)
{
    __shared__ float row[D_INNER];
    const int t = blockIdx.x;
    const float* xr = xi + (size_t)t * D_INNER;
    for (int i = threadIdx.x; i < D_INNER; i += 256) row[i] = xr[i];
    __syncthreads();

    const int wave = threadIdx.x >> 6;
    const int lane = threadIdx.x & 63;
    for (int e = wave; e < NDBL; e += 4) {
        const float* wr = W_x + (size_t)e * D_INNER;
        float s = 0.f;
        for (int i = lane; i < D_INNER; i += 64) s = fmaf(row[i], wr[i], s);
#pragma unroll
        for (int off = 32; off; off >>= 1) s += __shfl_xor(s, off);
        if (lane == 0) xdbl[(size_t)t * NDBL + e] = s;
    }
}

// ---------------------------------------------------------------------------
// Selective scan.  One thread per (b, d, n).  Block: 16 d x 16 n for one b.
// Reads xdbl (dt_raw, B, C), xi (conv output), xz (z half); writes gated y
// in-place into xi.
// ---------------------------------------------------------------------------
__launch_bounds__(256)
__global__ void scan_kernel(const float* __restrict__ xdbl,
                            float* __restrict__ xi,       // in: conv out, out: gated y
                            const float* __restrict__ xz, // z = second half of rows
                            const float* __restrict__ W_dt,
                            const float* __restrict__ b_dt,
                            const float* __restrict__ A_log,
                            const float* __restrict__ Dvec)
{
    const int tid  = threadIdx.x;
    const int n    = tid & 15;
    const int dloc = tid >> 4;
    const int d    = blockIdx.x * 16 + dloc;
    const int b    = blockIdx.y;

    const float A   = -expf(A_log[(size_t)d * D_STATE + n]);
    const float wdt = W_dt[d], bdt = b_dt[d], Dd = Dvec[d];

    const float* xd   = xdbl + (size_t)b * SEQ * NDBL;
    float*       xrow = xi + (size_t)b * SEQ * D_INNER + d;
    const float* zrow = xz + (size_t)b * SEQ * NXZ + D_INNER + d;

    float h = 0.f;
    for (int l = 0; l < SEQ; ++l) {
        const float* xr = xd + (size_t)l * NDBL;
        float raw = xr[0];
        float Bv  = xr[1 + n];
        float Cv  = xr[1 + D_STATE + n];
        float xv  = xrow[(size_t)l * D_INNER];

        float dtv = fmaf(raw, wdt, bdt);
        dtv = (dtv > 20.f) ? dtv : log1pf(expf(dtv));

        float dA = expf(dtv * A);
        h = fmaf(dA, h, (dtv * Bv) * xv);

        float p = h * Cv;
        p += __shfl_xor(p, 1);
        p += __shfl_xor(p, 2);
        p += __shfl_xor(p, 4);
        p += __shfl_xor(p, 8);

        if (n == 0) {
            float y  = p + Dd * xv;
            float zv = zrow[(size_t)l * NXZ];
            xrow[(size_t)l * D_INNER] = y * silu_f(zv);
        }
    }
}

// ---------------------------------------------------------------------------
extern "C" void kernel_launch(void* const* d_in, const int* in_sizes, int n_in,
                              void* d_out, int out_size, void* d_ws, size_t ws_size,
                              hipStream_t stream)
{
    (void)in_sizes; (void)n_in; (void)out_size; (void)ws_size;

    const float* x      = (const float*)d_in[0];
    const float* W_in   = (const float*)d_in[1];
    const float* conv_w = (const float*)d_in[2];
    const float* conv_b = (const float*)d_in[3];
    const float* W_x    = (const float*)d_in[4];
    const float* W_dt   = (const float*)d_in[5];
    const float* b_dt   = (const float*)d_in[6];
    const float* A_log  = (const float*)d_in[7];
    const float* Dvec   = (const float*)d_in[8];
    const float* W_out  = (const float*)d_in[9];
    float* out = (float*)d_out;

    float* xz   = (float*)d_ws;                       // NTOK x 4096
    float* xi   = xz + (size_t)NTOK * NXZ;            // NTOK x 2048
    float* xdbl = xi + (size_t)NTOK * D_INNER;        // NTOK x 33

    // 1) xz = x @ W_in^T   (M=4096, N=4096, K=1024)
    {
        dim3 grid(NXZ / 64, NTOK / 64);
        sgemm_nt<<<grid, 256, 0, stream>>>(x, W_in, xz, NTOK, NXZ, D_MODEL);
    }
    // 2) depthwise conv + SiLU -> xi
    {
        int total = NTOK * D_INNER;
        conv_silu_kernel<<<(total + 255) / 256, 256, 0, stream>>>(xz, conv_w, conv_b, xi);
    }
    // 3) x_dbl = xi @ W_x^T  (N=33)
    xdbl_kernel<<<NTOK, 256, 0, stream>>>(xi, W_x, xdbl);

    // 4) selective scan + D-skip + SiLU(z) gating, in-place into xi
    {
        dim3 grid(D_INNER / 16, BATCH);
        scan_kernel<<<grid, 256, 0, stream>>>(xdbl, xi, xz, W_dt, b_dt, A_log, Dvec);
    }
    // 5) out = y @ W_out^T  (M=4096, N=1024, K=2048)
    {
        dim3 grid(D_MODEL / 64, NTOK / 64);
        sgemm_nt<<<grid, 256, 0, stream>>>(xi, W_out, out, NTOK, D_MODEL, D_INNER);
    }
}

// Round 2
// 2141.967 us; speedup vs baseline: 1.4237x; 1.4237x over previous
//
#include <hip/hip_runtime.h>
#include <hip/hip_bf16.h>

#define D_MODEL 1024
#define D_STATE 16
#define D_CONV  4
#define D_INNER 2048
#define BATCH   2
#define SEQ     2048
#define NTOK    (BATCH * SEQ)      // 4096
#define NXZ     (2 * D_INNER)      // 4096
#define NDBL    (2 * D_STATE + 1)  // 33
#define CHUNK   64
#define NCHUNK  (SEQ / CHUNK)      // 32

__device__ __forceinline__ float silu_f(float x) { return x / (1.0f + expf(-x)); }
__device__ __forceinline__ float softplus_f(float x) {
    return (x > 20.f) ? x : log1pf(expf(x));
}

// ---------------------------------------------------------------------------
// C[M,N] = A[M,K] * B[N,K]^T   (both row-major; M,N multiples of 64, K of 16)
// BM=BN=64, BK=16, 256 threads, 4x4 per thread.
// ---------------------------------------------------------------------------
__launch_bounds__(256)
__global__ void sgemm_nt(const float* __restrict__ A, const float* __restrict__ B,
                         float* __restrict__ C, int M, int N, int K)
{
    constexpr int BM = 64, BN = 64, BK = 16, TM = 4, TN = 4;
    __shared__ float As[BK][BM + 1];
    __shared__ float Bs[BK][BN + 1];

    const int tid = threadIdx.x;
    const int tx = tid % (BN / TN);   // 0..15 (N dir)
    const int ty = tid / (BN / TN);   // 0..15 (M dir)
    const int bn = blockIdx.x, bm = blockIdx.y;

    const float* Ab = A + (size_t)bm * BM * K;
    const float* Bb = B + (size_t)bn * BN * K;

    const int lrow = tid >> 2;   // 0..63
    const int lseg = tid & 3;    // 0..3  (float4 segment within BK=16)

    float acc[TM][TN] = {};

    for (int k0 = 0; k0 < K; k0 += BK) {
        float4 av = *(const float4*)(Ab + (size_t)lrow * K + k0 + lseg * 4);
        float4 bv = *(const float4*)(Bb + (size_t)lrow * K + k0 + lseg * 4);
        As[lseg * 4 + 0][lrow] = av.x; As[lseg * 4 + 1][lrow] = av.y;
        As[lseg * 4 + 2][lrow] = av.z; As[lseg * 4 + 3][lrow] = av.w;
        Bs[lseg * 4 + 0][lrow] = bv.x; Bs[lseg * 4 + 1][lrow] = bv.y;
        Bs[lseg * 4 + 2][lrow] = bv.z; Bs[lseg * 4 + 3][lrow] = bv.w;
        __syncthreads();

#pragma unroll
        for (int k = 0; k < BK; ++k) {
            float am[TM], bnv[TN];
#pragma unroll
            for (int i = 0; i < TM; ++i) am[i] = As[k][ty * TM + i];
#pragma unroll
            for (int j = 0; j < TN; ++j) bnv[j] = Bs[k][tx * TN + j];
#pragma unroll
            for (int i = 0; i < TM; ++i)
#pragma unroll
                for (int j = 0; j < TN; ++j)
                    acc[i][j] = fmaf(am[i], bnv[j], acc[i][j]);
        }
        __syncthreads();
    }

#pragma unroll
    for (int i = 0; i < TM; ++i) {
        float4 o = make_float4(acc[i][0], acc[i][1], acc[i][2], acc[i][3]);
        *(float4*)(C + (size_t)(bm * BM + ty * TM + i) * N + bn * BN + tx * TN) = o;
    }
}

// ---------------------------------------------------------------------------
// Depthwise causal conv (k=4) + bias + SiLU.  Input: first half of xz rows.
// ---------------------------------------------------------------------------
__global__ void conv_silu_kernel(const float* __restrict__ xz,
                                 const float* __restrict__ conv_w,
                                 const float* __restrict__ conv_b,
                                 float* __restrict__ xi)
{
    int idx = blockIdx.x * blockDim.x + threadIdx.x;
    if (idx >= NTOK * D_INNER) return;
    int d = idx % D_INNER;
    int t = idx / D_INNER;
    int l = t % SEQ;
    int b = t / SEQ;

    float w0 = conv_w[d * 4 + 0], w1 = conv_w[d * 4 + 1];
    float w2 = conv_w[d * 4 + 2], w3 = conv_w[d * 4 + 3];

    const float* base = xz + ((size_t)b * SEQ) * NXZ + d;  // channel-d column
    float acc = conv_b[d];
    if (l >= 3) acc = fmaf(w0, base[(size_t)(l - 3) * NXZ], acc);
    if (l >= 2) acc = fmaf(w1, base[(size_t)(l - 2) * NXZ], acc);
    if (l >= 1) acc = fmaf(w2, base[(size_t)(l - 1) * NXZ], acc);
    acc = fmaf(w3, base[(size_t)l * NXZ], acc);
    xi[idx] = silu_f(acc);
}

// ---------------------------------------------------------------------------
// x_dbl[t, e] = sum_d xi[t,d] * W_x[e,d],  e in [0,33).  Block per token.
// ---------------------------------------------------------------------------
__launch_bounds__(256)
__global__ void xdbl_kernel(const float* __restrict__ xi,
                            const float* __restrict__ W_x,
                            float* __restrict__ xdbl)
{
    __shared__ float row[D_INNER];
    const int t = blockIdx.x;
    const float* xr = xi + (size_t)t * D_INNER;
    for (int i = threadIdx.x; i < D_INNER; i += 256) row[i] = xr[i];
    __syncthreads();

    const int wave = threadIdx.x >> 6;
    const int lane = threadIdx.x & 63;
    for (int e = wave; e < NDBL; e += 4) {
        const float* wr = W_x + (size_t)e * D_INNER;
        float s = 0.f;
        for (int i = lane; i < D_INNER; i += 64) s = fmaf(row[i], wr[i], s);
#pragma unroll
        for (int off = 32; off; off >>= 1) s += __shfl_xor(s, off);
        if (lane == 0) xdbl[(size_t)t * NDBL + e] = s;
    }
}

// ---------------------------------------------------------------------------
// Chunked selective scan, pass 1: per-chunk local scan from h=0.
// Records prod(dA) and local end state for each (b, chunk, d, n).
// Block = 16 d x 16 n; grid = (D_INNER/16, NCHUNK, BATCH).
// ---------------------------------------------------------------------------
__launch_bounds__(256)
__global__ void scan_pass1(const float* __restrict__ xdbl,
                           const float* __restrict__ xi,
                           const float* __restrict__ W_dt,
                           const float* __restrict__ b_dt,
                           const float* __restrict__ A_log,
                           float* __restrict__ aprod,
                           float* __restrict__ hloc)
{
    const int tid  = threadIdx.x;
    const int n    = tid & 15;
    const int dloc = tid >> 4;
    const int d    = blockIdx.x * 16 + dloc;
    const int c    = blockIdx.y;
    const int b    = blockIdx.z;

    const float A   = -expf(A_log[(size_t)d * D_STATE + n]);
    const float wdt = W_dt[d], bdt = b_dt[d];

    const int l0 = c * CHUNK;
    const float* xd   = xdbl + ((size_t)b * SEQ + l0) * NDBL;
    const float* xrow = xi + ((size_t)b * SEQ + l0) * D_INNER + d;

    float h = 0.f, ap = 1.f;
#pragma unroll 4
    for (int l = 0; l < CHUNK; ++l) {
        float raw = xd[l * NDBL];
        float Bv  = xd[l * NDBL + 1 + n];
        float xv  = xrow[(size_t)l * D_INNER];
        float dtv = softplus_f(fmaf(raw, wdt, bdt));
        float dA  = expf(dtv * A);
        h  = fmaf(dA, h, (dtv * Bv) * xv);
        ap *= dA;
    }
    size_t idx = ((((size_t)b * NCHUNK + c) * D_INNER + d) << 4) + n;
    aprod[idx] = ap;
    hloc[idx]  = h;
}

// ---------------------------------------------------------------------------
// Chunked scan, combine: sequential scan over the 32 chunk summaries.
// One thread per (b, d, n) = 65536.  Writes h_start for every chunk.
// ---------------------------------------------------------------------------
__global__ void scan_combine(const float* __restrict__ aprod,
                             const float* __restrict__ hloc,
                             float* __restrict__ hstart)
{
    int idx = blockIdx.x * blockDim.x + threadIdx.x;  // b*32768 + d*16 + n
    int b  = idx >> 15;
    int dn = idx & 32767;
    float hs = 0.f;
#pragma unroll
    for (int c = 0; c < NCHUNK; ++c) {
        size_t s = (((size_t)b * NCHUNK + c) << 15) + dn;
        hstart[s] = hs;
        hs = fmaf(aprod[s], hs, hloc[s]);
    }
}

// ---------------------------------------------------------------------------
// Chunked scan, pass 2: rescan each chunk from its true h_start; emit gated y.
// ---------------------------------------------------------------------------
__launch_bounds__(256)
__global__ void scan_pass2(const float* __restrict__ xdbl,
                           float* __restrict__ xi,        // in: conv out, out: gated y
                           const float* __restrict__ xz,  // z half
                           const float* __restrict__ W_dt,
                           const float* __restrict__ b_dt,
                           const float* __restrict__ A_log,
                           const float* __restrict__ Dvec,
                           const float* __restrict__ hstart)
{
    const int tid  = threadIdx.x;
    const int n    = tid & 15;
    const int dloc = tid >> 4;
    const int d    = blockIdx.x * 16 + dloc;
    const int c    = blockIdx.y;
    const int b    = blockIdx.z;

    const float A   = -expf(A_log[(size_t)d * D_STATE + n]);
    const float wdt = W_dt[d], bdt = b_dt[d], Dd = Dvec[d];

    const int l0 = c * CHUNK;
    const float* xd   = xdbl + ((size_t)b * SEQ + l0) * NDBL;
    float*       xrow = xi + ((size_t)b * SEQ + l0) * D_INNER + d;
    const float* zrow = xz + ((size_t)b * SEQ + l0) * NXZ + D_INNER + d;

    size_t sidx = ((((size_t)b * NCHUNK + c) * D_INNER + d) << 4) + n;
    float h = hstart[sidx];

#pragma unroll 4
    for (int l = 0; l < CHUNK; ++l) {
        float raw = xd[l * NDBL];
        float Bv  = xd[l * NDBL + 1 + n];
        float Cv  = xd[l * NDBL + 1 + D_STATE + n];
        float xv  = xrow[(size_t)l * D_INNER];
        float dtv = softplus_f(fmaf(raw, wdt, bdt));
        float dA  = expf(dtv * A);
        h = fmaf(dA, h, (dtv * Bv) * xv);

        float p = h * Cv;
        p += __shfl_xor(p, 1);
        p += __shfl_xor(p, 2);
        p += __shfl_xor(p, 4);
        p += __shfl_xor(p, 8);

        if (n == 0) {
            float y  = p + Dd * xv;
            float zv = zrow[(size_t)l * NXZ];
            xrow[(size_t)l * D_INNER] = y * silu_f(zv);
        }
    }
}

// ---------------------------------------------------------------------------
extern "C" void kernel_launch(void* const* d_in, const int* in_sizes, int n_in,
                              void* d_out, int out_size, void* d_ws, size_t ws_size,
                              hipStream_t stream)
{
    (void)in_sizes; (void)n_in; (void)out_size; (void)ws_size;

    const float* x      = (const float*)d_in[0];
    const float* W_in   = (const float*)d_in[1];
    const float* conv_w = (const float*)d_in[2];
    const float* conv_b = (const float*)d_in[3];
    const float* W_x    = (const float*)d_in[4];
    const float* W_dt   = (const float*)d_in[5];
    const float* b_dt   = (const float*)d_in[6];
    const float* A_log  = (const float*)d_in[7];
    const float* Dvec   = (const float*)d_in[8];
    const float* W_out  = (const float*)d_in[9];
    float* out = (float*)d_out;

    float* xz     = (float*)d_ws;                         // NTOK x 4096
    float* xi     = xz + (size_t)NTOK * NXZ;              // NTOK x 2048
    float* xdbl   = xi + (size_t)NTOK * D_INNER;          // NTOK x 33
    float* aprod  = xdbl + (size_t)NTOK * NDBL;           // B x NCHUNK x D_INNER x 16
    float* hloc   = aprod + (size_t)BATCH * NCHUNK * D_INNER * 16;
    float* hstart = hloc + (size_t)BATCH * NCHUNK * D_INNER * 16;

    // 1) xz = x @ W_in^T   (M=4096, N=4096, K=1024)
    {
        dim3 grid(NXZ / 64, NTOK / 64);
        sgemm_nt<<<grid, 256, 0, stream>>>(x, W_in, xz, NTOK, NXZ, D_MODEL);
    }
    // 2) depthwise conv + SiLU -> xi
    {
        int total = NTOK * D_INNER;
        conv_silu_kernel<<<(total + 255) / 256, 256, 0, stream>>>(xz, conv_w, conv_b, xi);
    }
    // 3) x_dbl = xi @ W_x^T  (N=33)
    xdbl_kernel<<<NTOK, 256, 0, stream>>>(xi, W_x, xdbl);

    // 4) chunked selective scan
    {
        dim3 grid(D_INNER / 16, NCHUNK, BATCH);
        scan_pass1<<<grid, 256, 0, stream>>>(xdbl, xi, W_dt, b_dt, A_log, aprod, hloc);
        scan_combine<<<(BATCH * D_INNER * 16) / 256, 256, 0, stream>>>(aprod, hloc, hstart);
        scan_pass2<<<grid, 256, 0, stream>>>(xdbl, xi, xz, W_dt, b_dt, A_log, Dvec, hstart);
    }
    // 5) out = y @ W_out^T  (M=4096, N=1024, K=2048)
    {
        dim3 grid(D_MODEL / 64, NTOK / 64);
        sgemm_nt<<<grid, 256, 0, stream>>>(xi, W_out, out, NTOK, D_MODEL, D_INNER);
    }
}

// Round 5
// 1500.851 us; speedup vs baseline: 2.0319x; 1.4272x over previous
//
#include <hip/hip_runtime.h>
#include <hip/hip_bf16.h>

#define D_MODEL 1024
#define D_STATE 16
#define D_CONV  4
#define D_INNER 2048
#define BATCH   2
#define SEQ     2048
#define NTOK    (BATCH * SEQ)      // 4096
#define NXZ     (2 * D_INNER)      // 4096
#define NDBL    (2 * D_STATE + 1)  // 33
#define CHUNK   64
#define NCHUNK  (SEQ / CHUNK)      // 32

typedef __attribute__((ext_vector_type(8))) short bf16x8;
typedef __attribute__((ext_vector_type(4))) float f32x4;

__device__ __forceinline__ float silu_f(float x) { return x / (1.0f + expf(-x)); }
__device__ __forceinline__ float softplus_f(float x) {
    return (x > 20.f) ? x : log1pf(expf(x));
}
__device__ __forceinline__ short f2bf(float f) {
    __hip_bfloat16 h = __float2bfloat16(f);
    return __builtin_bit_cast(short, h);
}
__device__ __forceinline__ float bf2f(short s) {
    return __bfloat162float(__builtin_bit_cast(__hip_bfloat16, s));
}
__device__ __forceinline__ void gload_lds16(const void* g, void* l) {
    __builtin_amdgcn_global_load_lds(
        (const __attribute__((address_space(1))) void*)g,
        (__attribute__((address_space(3))) void*)l, 16, 0, 0);
}

// ---------------------------------------------------------------------------
// Split fp32 -> (hi, lo) bf16 pair.  n4 = count/4.
// ---------------------------------------------------------------------------
__global__ void split_kernel(const float* __restrict__ in, short* __restrict__ hi,
                             short* __restrict__ lo, int n4)
{
    int i = blockIdx.x * blockDim.x + threadIdx.x;
    if (i >= n4) return;
    float4 v = ((const float4*)in)[i];
    short4 h, l;
    h.x = f2bf(v.x); l.x = f2bf(v.x - bf2f(h.x));
    h.y = f2bf(v.y); l.y = f2bf(v.y - bf2f(h.y));
    h.z = f2bf(v.z); l.z = f2bf(v.z - bf2f(h.z));
    h.w = f2bf(v.w); l.w = f2bf(v.w - bf2f(h.w));
    ((short4*)hi)[i] = h;
    ((short4*)lo)[i] = l;
}

// ---------------------------------------------------------------------------
// Split-bf16 MFMA GEMM: C[M,N] = A[M,K] * B[N,K]^T  (fp32-accurate via hi/lo).
// 128x128 tile, BK=32, 256 threads = 4 waves (2x2), each wave 64x64 out.
// LDS granule-major [4 granules][128 rows][8 bf16] per array: linear
// global_load_lds dest AND conflict-free ds_read_b128 fragment reads.
// ---------------------------------------------------------------------------
__launch_bounds__(256, 2)
__global__ void mfma_gemm_split(const short* __restrict__ Ahi, const short* __restrict__ Alo,
                                const short* __restrict__ Bhi, const short* __restrict__ Blo,
                                float* __restrict__ C, int M, int N, int K)
{
    __shared__ short sAh[4096], sAl[4096], sBh[4096], sBl[4096];
    const int tid  = threadIdx.x;
    const int lane = tid & 63;
    const int wave = tid >> 6;
    const int bm = blockIdx.y, bn = blockIdx.x;
    const int wm = wave >> 1, wn = wave & 1;

    const int r0a = bm * 128, r0b = bn * 128;

    f32x4 acc[4][4] = {};

    for (int k0 = 0; k0 < K; k0 += 32) {
        __syncthreads();  // previous iteration's readers done before overwrite
#pragma unroll
        for (int i = 0; i < 2; ++i) {
            const int off = i * 4096 + tid * 16;   // LDS byte offset this lane fills
            const int g   = off >> 11;             // granule 0..3
            const int row = (off >> 4) & 127;      // tile row 0..127
            const size_t ea = (size_t)(r0a + row) * K + k0 + g * 8;
            const size_t eb = (size_t)(r0b + row) * K + k0 + g * 8;
            char* la = (char*)sAh + i * 4096 + wave * 1024;  // wave-uniform base
            gload_lds16(Ahi + ea, la);
            gload_lds16(Alo + ea, (char*)sAl + i * 4096 + wave * 1024);
            gload_lds16(Bhi + eb, (char*)sBh + i * 4096 + wave * 1024);
            gload_lds16(Blo + eb, (char*)sBl + i * 4096 + wave * 1024);
        }
        __syncthreads();  // staging (vmcnt) drained

        const int g = lane >> 4;
        bf16x8 ah[4], al[4], bh[4], bl[4];
#pragma unroll
        for (int m = 0; m < 4; ++m) {
            const int rowA = wm * 64 + m * 16 + (lane & 15);
            const int rowB = wn * 64 + m * 16 + (lane & 15);
            ah[m] = ((const bf16x8*)sAh)[g * 128 + rowA];
            al[m] = ((const bf16x8*)sAl)[g * 128 + rowA];
            bh[m] = ((const bf16x8*)sBh)[g * 128 + rowB];
            bl[m] = ((const bf16x8*)sBl)[g * 128 + rowB];
        }
#pragma unroll
        for (int m = 0; m < 4; ++m)
#pragma unroll
            for (int n = 0; n < 4; ++n) {
                acc[m][n] = __builtin_amdgcn_mfma_f32_16x16x32_bf16(ah[m], bh[n], acc[m][n], 0, 0, 0);
                acc[m][n] = __builtin_amdgcn_mfma_f32_16x16x32_bf16(ah[m], bl[n], acc[m][n], 0, 0, 0);
                acc[m][n] = __builtin_amdgcn_mfma_f32_16x16x32_bf16(al[m], bh[n], acc[m][n], 0, 0, 0);
            }
    }

    // epilogue: C/D layout col=lane&15, row=(lane>>4)*4+reg
#pragma unroll
    for (int m = 0; m < 4; ++m) {
        const int row = bm * 128 + wm * 64 + m * 16 + ((lane >> 4) << 2);
#pragma unroll
        for (int n = 0; n < 4; ++n) {
            const int col = bn * 128 + wn * 64 + n * 16 + (lane & 15);
#pragma unroll
            for (int r = 0; r < 4; ++r)
                C[(size_t)(row + r) * N + col] = acc[m][n][r];
        }
    }
}

// ---------------------------------------------------------------------------
// Depthwise causal conv (k=4) + bias + SiLU.
// ---------------------------------------------------------------------------
__global__ void conv_silu_kernel(const float* __restrict__ xz,
                                 const float* __restrict__ conv_w,
                                 const float* __restrict__ conv_b,
                                 float* __restrict__ xi)
{
    int idx = blockIdx.x * blockDim.x + threadIdx.x;
    if (idx >= NTOK * D_INNER) return;
    int d = idx % D_INNER;
    int t = idx / D_INNER;
    int l = t % SEQ;
    int b = t / SEQ;

    float w0 = conv_w[d * 4 + 0], w1 = conv_w[d * 4 + 1];
    float w2 = conv_w[d * 4 + 2], w3 = conv_w[d * 4 + 3];

    const float* base = xz + ((size_t)b * SEQ) * NXZ + d;
    float acc = conv_b[d];
    if (l >= 3) acc = fmaf(w0, base[(size_t)(l - 3) * NXZ], acc);
    if (l >= 2) acc = fmaf(w1, base[(size_t)(l - 2) * NXZ], acc);
    if (l >= 1) acc = fmaf(w2, base[(size_t)(l - 1) * NXZ], acc);
    acc = fmaf(w3, base[(size_t)l * NXZ], acc);
    xi[idx] = silu_f(acc);
}

// ---------------------------------------------------------------------------
// x_dbl[t, e] = sum_d xi[t,d] * W_x[e,d],  e in [0,33).  Block per token.
// ---------------------------------------------------------------------------
__launch_bounds__(256)
__global__ void xdbl_kernel(const float* __restrict__ xi,
                            const float* __restrict__ W_x,
                            float* __restrict__ xdbl)
{
    __shared__ float row[D_INNER];
    const int t = blockIdx.x;
    const float* xr = xi + (size_t)t * D_INNER;
    for (int i = threadIdx.x; i < D_INNER; i += 256) row[i] = xr[i];
    __syncthreads();

    const int wave = threadIdx.x >> 6;
    const int lane = threadIdx.x & 63;
    for (int e = wave; e < NDBL; e += 4) {
        const float* wr = W_x + (size_t)e * D_INNER;
        float s = 0.f;
        for (int i = lane; i < D_INNER; i += 64) s = fmaf(row[i], wr[i], s);
#pragma unroll
        for (int off = 32; off; off >>= 1) s += __shfl_xor(s, off);
        if (lane == 0) xdbl[(size_t)t * NDBL + e] = s;
    }
}

// ---------------------------------------------------------------------------
// Chunked scan pass 1: per-chunk local scan from h=0; record prod(dA), h_end.
// ---------------------------------------------------------------------------
__launch_bounds__(256)
__global__ void scan_pass1(const float* __restrict__ xdbl,
                           const float* __restrict__ xi,
                           const float* __restrict__ W_dt,
                           const float* __restrict__ b_dt,
                           const float* __restrict__ A_log,
                           float* __restrict__ aprod,
                           float* __restrict__ hloc)
{
    const int tid  = threadIdx.x;
    const int n    = tid & 15;
    const int dloc = tid >> 4;
    const int d    = blockIdx.x * 16 + dloc;
    const int c    = blockIdx.y;
    const int b    = blockIdx.z;

    const float A   = -expf(A_log[(size_t)d * D_STATE + n]);
    const float wdt = W_dt[d], bdt = b_dt[d];

    const int l0 = c * CHUNK;
    const float* xd   = xdbl + ((size_t)b * SEQ + l0) * NDBL;
    const float* xrow = xi + ((size_t)b * SEQ + l0) * D_INNER + d;

    float h = 0.f, ap = 1.f;
#pragma unroll 4
    for (int l = 0; l < CHUNK; ++l) {
        float raw = xd[l * NDBL];
        float Bv  = xd[l * NDBL + 1 + n];
        float xv  = xrow[(size_t)l * D_INNER];
        float dtv = softplus_f(fmaf(raw, wdt, bdt));
        float dA  = expf(dtv * A);
        h  = fmaf(dA, h, (dtv * Bv) * xv);
        ap *= dA;
    }
    size_t idx = ((((size_t)b * NCHUNK + c) * D_INNER + d) << 4) + n;
    aprod[idx] = ap;
    hloc[idx]  = h;
}

// ---------------------------------------------------------------------------
// Chunked scan combine: serial over 32 chunk summaries; h_start per chunk.
// ---------------------------------------------------------------------------
__global__ void scan_combine(const float* __restrict__ aprod,
                             const float* __restrict__ hloc,
                             float* __restrict__ hstart)
{
    int idx = blockIdx.x * blockDim.x + threadIdx.x;  // b*32768 + d*16 + n
    int b  = idx >> 15;
    int dn = idx & 32767;
    float hs = 0.f;
#pragma unroll
    for (int c = 0; c < NCHUNK; ++c) {
        size_t s = (((size_t)b * NCHUNK + c) << 15) + dn;
        hstart[s] = hs;
        hs = fmaf(aprod[s], hs, hloc[s]);
    }
}

// ---------------------------------------------------------------------------
// Chunked scan pass 2: rescan from h_start; emit gated y in-place into xi.
// ---------------------------------------------------------------------------
__launch_bounds__(256)
__global__ void scan_pass2(const float* __restrict__ xdbl,
                           float* __restrict__ xi,
                           const float* __restrict__ xz,
                           const float* __restrict__ W_dt,
                           const float* __restrict__ b_dt,
                           const float* __restrict__ A_log,
                           const float* __restrict__ Dvec,
                           const float* __restrict__ hstart)
{
    const int tid  = threadIdx.x;
    const int n    = tid & 15;
    const int dloc = tid >> 4;
    const int d    = blockIdx.x * 16 + dloc;
    const int c    = blockIdx.y;
    const int b    = blockIdx.z;

    const float A   = -expf(A_log[(size_t)d * D_STATE + n]);
    const float wdt = W_dt[d], bdt = b_dt[d], Dd = Dvec[d];

    const int l0 = c * CHUNK;
    const float* xd   = xdbl + ((size_t)b * SEQ + l0) * NDBL;
    float*       xrow = xi + ((size_t)b * SEQ + l0) * D_INNER + d;
    const float* zrow = xz + ((size_t)b * SEQ + l0) * NXZ + D_INNER + d;

    size_t sidx = ((((size_t)b * NCHUNK + c) * D_INNER + d) << 4) + n;
    float h = hstart[sidx];

#pragma unroll 4
    for (int l = 0; l < CHUNK; ++l) {
        float raw = xd[l * NDBL];
        float Bv  = xd[l * NDBL + 1 + n];
        float Cv  = xd[l * NDBL + 1 + D_STATE + n];
        float xv  = xrow[(size_t)l * D_INNER];
        float dtv = softplus_f(fmaf(raw, wdt, bdt));
        float dA  = expf(dtv * A);
        h = fmaf(dA, h, (dtv * Bv) * xv);

        float p = h * Cv;
        p += __shfl_xor(p, 1);
        p += __shfl_xor(p, 2);
        p += __shfl_xor(p, 4);
        p += __shfl_xor(p, 8);

        if (n == 0) {
            float y  = p + Dd * xv;
            float zv = zrow[(size_t)l * NXZ];
            xrow[(size_t)l * D_INNER] = y * silu_f(zv);
        }
    }
}

// ---------------------------------------------------------------------------
extern "C" void kernel_launch(void* const* d_in, const int* in_sizes, int n_in,
                              void* d_out, int out_size, void* d_ws, size_t ws_size,
                              hipStream_t stream)
{
    (void)in_sizes; (void)n_in; (void)out_size; (void)ws_size;

    const float* x      = (const float*)d_in[0];
    const float* W_in   = (const float*)d_in[1];
    const float* conv_w = (const float*)d_in[2];
    const float* conv_b = (const float*)d_in[3];
    const float* W_x    = (const float*)d_in[4];
    const float* W_dt   = (const float*)d_in[5];
    const float* b_dt   = (const float*)d_in[6];
    const float* A_log  = (const float*)d_in[7];
    const float* Dvec   = (const float*)d_in[8];
    const float* W_out  = (const float*)d_in[9];
    float* out = (float*)d_out;

    // ---- workspace map ----
    float* xz   = (float*)d_ws;                    // 4096x4096 f32 (64MB)
    float* xi   = xz + (size_t)NTOK * NXZ;         // 4096x2048 f32 (32MB)
    float* xdbl = xi + (size_t)NTOK * D_INNER;     // 4096x33 f32
    float* R    = xdbl + (size_t)NTOK * NDBL;      // 32MB shared region

    // phase-1 occupants of R: hi/lo splits of x and W_in
    short* x_hi   = (short*)R;
    short* x_lo   = x_hi + (size_t)NTOK * D_MODEL;
    short* Win_hi = x_lo + (size_t)NTOK * D_MODEL;
    short* Win_lo = Win_hi + (size_t)NXZ * D_MODEL;
    // phase-2 occupants of R (x/W_in splits dead after GEMM1): scan buffers
    float* aprod  = R;
    float* hloc   = aprod + (size_t)BATCH * NCHUNK * D_INNER * 16;
    float* hstart = hloc + (size_t)BATCH * NCHUNK * D_INNER * 16;
    // phase-3 occupants of xz region (z consumed by pass2): y / W_out splits
    short* y_hi   = (short*)xz;
    short* y_lo   = y_hi + (size_t)NTOK * D_INNER;
    short* Wou_hi = y_lo + (size_t)NTOK * D_INNER;
    short* Wou_lo = Wou_hi + (size_t)D_MODEL * D_INNER;

    // 0) split x and W_in to bf16 hi/lo
    split_kernel<<<(NTOK * D_MODEL / 4 + 255) / 256, 256, 0, stream>>>(x, x_hi, x_lo, NTOK * D_MODEL / 4);
    split_kernel<<<(NXZ * D_MODEL / 4 + 255) / 256, 256, 0, stream>>>(W_in, Win_hi, Win_lo, NXZ * D_MODEL / 4);

    // 1) xz = x @ W_in^T   (M=4096, N=4096, K=1024)
    {
        dim3 grid(NXZ / 128, NTOK / 128);
        mfma_gemm_split<<<grid, 256, 0, stream>>>(x_hi, x_lo, Win_hi, Win_lo, xz, NTOK, NXZ, D_MODEL);
    }
    // 2) depthwise conv + SiLU -> xi
    {
        int total = NTOK * D_INNER;
        conv_silu_kernel<<<(total + 255) / 256, 256, 0, stream>>>(xz, conv_w, conv_b, xi);
    }
    // 3) x_dbl = xi @ W_x^T  (N=33)
    xdbl_kernel<<<NTOK, 256, 0, stream>>>(xi, W_x, xdbl);

    // 4) chunked selective scan (R now holds aprod/hloc/hstart)
    {
        dim3 grid(D_INNER / 16, NCHUNK, BATCH);
        scan_pass1<<<grid, 256, 0, stream>>>(xdbl, xi, W_dt, b_dt, A_log, aprod, hloc);
        scan_combine<<<(BATCH * D_INNER * 16) / 256, 256, 0, stream>>>(aprod, hloc, hstart);
        scan_pass2<<<grid, 256, 0, stream>>>(xdbl, xi, xz, W_dt, b_dt, A_log, Dvec, hstart);
    }
    // 5) split y (=xi) and W_out, then out = y @ W_out^T  (M=4096, N=1024, K=2048)
    split_kernel<<<(NTOK * D_INNER / 4 + 255) / 256, 256, 0, stream>>>(xi, y_hi, y_lo, NTOK * D_INNER / 4);
    split_kernel<<<(D_MODEL * D_INNER / 4 + 255) / 256, 256, 0, stream>>>(W_out, Wou_hi, Wou_lo, D_MODEL * D_INNER / 4);
    {
        dim3 grid(D_MODEL / 128, NTOK / 128);
        mfma_gemm_split<<<grid, 256, 0, stream>>>(y_hi, y_lo, Wou_hi, Wou_lo, out, NTOK, D_MODEL, D_INNER);
    }
}

// Round 6
// 877.010 us; speedup vs baseline: 3.4773x; 1.7113x over previous
//
#include <hip/hip_runtime.h>
#include <hip/hip_bf16.h>

#define D_MODEL 1024
#define D_STATE 16
#define D_CONV  4
#define D_INNER 2048
#define BATCH   2
#define SEQ     2048
#define NTOK    (BATCH * SEQ)      // 4096
#define NXZ     (2 * D_INNER)      // 4096
#define NDBL    (2 * D_STATE + 1)  // 33
#define CHUNK   64
#define NCHUNK  (SEQ / CHUNK)      // 32

typedef __attribute__((ext_vector_type(8))) short bf16x8;
typedef __attribute__((ext_vector_type(4))) float f32x4;

// Fast transcendentals: v_exp_f32 / v_log_f32 (4-cycle trans ops) instead of
// libm call sequences.  Error ~1e-6 relative, negligible vs 0.0156 budget.
__device__ __forceinline__ float silu_fast(float x) {
    return x / (1.0f + __expf(-x));
}
__device__ __forceinline__ float softplus_fast(float x) {
    float r = __logf(1.0f + __expf(x));
    return (x > 20.f) ? x : r;
}
__device__ __forceinline__ short f2bf(float f) {
    __hip_bfloat16 h = __float2bfloat16(f);
    return __builtin_bit_cast(short, h);
}
__device__ __forceinline__ float bf2f(short s) {
    return __bfloat162float(__builtin_bit_cast(__hip_bfloat16, s));
}
__device__ __forceinline__ void gload_lds16(const void* g, void* l) {
    __builtin_amdgcn_global_load_lds(
        (const __attribute__((address_space(1))) void*)g,
        (__attribute__((address_space(3))) void*)l, 16, 0, 0);
}

// ---------------------------------------------------------------------------
// Split fp32 -> (hi, lo) bf16 pair.  n4 = count/4.
// ---------------------------------------------------------------------------
__global__ void split_kernel(const float* __restrict__ in, short* __restrict__ hi,
                             short* __restrict__ lo, int n4)
{
    int i = blockIdx.x * blockDim.x + threadIdx.x;
    if (i >= n4) return;
    float4 v = ((const float4*)in)[i];
    short4 h, l;
    h.x = f2bf(v.x); l.x = f2bf(v.x - bf2f(h.x));
    h.y = f2bf(v.y); l.y = f2bf(v.y - bf2f(h.y));
    h.z = f2bf(v.z); l.z = f2bf(v.z - bf2f(h.z));
    h.w = f2bf(v.w); l.w = f2bf(v.w - bf2f(h.w));
    ((short4*)hi)[i] = h;
    ((short4*)lo)[i] = l;
}

// ---------------------------------------------------------------------------
// Split-bf16 MFMA GEMM: C[M,N] = A[M,K] * B[N,K]^T  (fp32-accurate via hi/lo).
// 128x128 tile, BK=32, 256 threads = 4 waves (2x2), each wave 64x64 out.
// ---------------------------------------------------------------------------
__launch_bounds__(256, 2)
__global__ void mfma_gemm_split(const short* __restrict__ Ahi, const short* __restrict__ Alo,
                                const short* __restrict__ Bhi, const short* __restrict__ Blo,
                                float* __restrict__ C, int M, int N, int K)
{
    __shared__ short sAh[4096], sAl[4096], sBh[4096], sBl[4096];
    const int tid  = threadIdx.x;
    const int lane = tid & 63;
    const int wave = tid >> 6;
    const int bm = blockIdx.y, bn = blockIdx.x;
    const int wm = wave >> 1, wn = wave & 1;

    const int r0a = bm * 128, r0b = bn * 128;

    f32x4 acc[4][4] = {};

    for (int k0 = 0; k0 < K; k0 += 32) {
        __syncthreads();
#pragma unroll
        for (int i = 0; i < 2; ++i) {
            const int off = i * 4096 + tid * 16;
            const int g   = off >> 11;
            const int row = (off >> 4) & 127;
            const size_t ea = (size_t)(r0a + row) * K + k0 + g * 8;
            const size_t eb = (size_t)(r0b + row) * K + k0 + g * 8;
            char* la = (char*)sAh + i * 4096 + wave * 1024;
            gload_lds16(Ahi + ea, la);
            gload_lds16(Alo + ea, (char*)sAl + i * 4096 + wave * 1024);
            gload_lds16(Bhi + eb, (char*)sBh + i * 4096 + wave * 1024);
            gload_lds16(Blo + eb, (char*)sBl + i * 4096 + wave * 1024);
        }
        __syncthreads();

        const int g = lane >> 4;
        bf16x8 ah[4], al[4], bh[4], bl[4];
#pragma unroll
        for (int m = 0; m < 4; ++m) {
            const int rowA = wm * 64 + m * 16 + (lane & 15);
            const int rowB = wn * 64 + m * 16 + (lane & 15);
            ah[m] = ((const bf16x8*)sAh)[g * 128 + rowA];
            al[m] = ((const bf16x8*)sAl)[g * 128 + rowA];
            bh[m] = ((const bf16x8*)sBh)[g * 128 + rowB];
            bl[m] = ((const bf16x8*)sBl)[g * 128 + rowB];
        }
#pragma unroll
        for (int m = 0; m < 4; ++m)
#pragma unroll
            for (int n = 0; n < 4; ++n) {
                acc[m][n] = __builtin_amdgcn_mfma_f32_16x16x32_bf16(ah[m], bh[n], acc[m][n], 0, 0, 0);
                acc[m][n] = __builtin_amdgcn_mfma_f32_16x16x32_bf16(ah[m], bl[n], acc[m][n], 0, 0, 0);
                acc[m][n] = __builtin_amdgcn_mfma_f32_16x16x32_bf16(al[m], bh[n], acc[m][n], 0, 0, 0);
            }
    }

#pragma unroll
    for (int m = 0; m < 4; ++m) {
        const int row = bm * 128 + wm * 64 + m * 16 + ((lane >> 4) << 2);
#pragma unroll
        for (int n = 0; n < 4; ++n) {
            const int col = bn * 128 + wn * 64 + n * 16 + (lane & 15);
#pragma unroll
            for (int r = 0; r < 4; ++r)
                C[(size_t)(row + r) * N + col] = acc[m][n][r];
        }
    }
}

// ---------------------------------------------------------------------------
// Depthwise causal conv (k=4) + bias + SiLU (fast).
// ---------------------------------------------------------------------------
__global__ void conv_silu_kernel(const float* __restrict__ xz,
                                 const float* __restrict__ conv_w,
                                 const float* __restrict__ conv_b,
                                 float* __restrict__ xi)
{
    int idx = blockIdx.x * blockDim.x + threadIdx.x;
    if (idx >= NTOK * D_INNER) return;
    int d = idx % D_INNER;
    int t = idx / D_INNER;
    int l = t % SEQ;
    int b = t / SEQ;

    float w0 = conv_w[d * 4 + 0], w1 = conv_w[d * 4 + 1];
    float w2 = conv_w[d * 4 + 2], w3 = conv_w[d * 4 + 3];

    const float* base = xz + ((size_t)b * SEQ) * NXZ + d;
    float acc = conv_b[d];
    if (l >= 3) acc = fmaf(w0, base[(size_t)(l - 3) * NXZ], acc);
    if (l >= 2) acc = fmaf(w1, base[(size_t)(l - 2) * NXZ], acc);
    if (l >= 1) acc = fmaf(w2, base[(size_t)(l - 1) * NXZ], acc);
    acc = fmaf(w3, base[(size_t)l * NXZ], acc);
    xi[idx] = silu_fast(acc);
}

// ---------------------------------------------------------------------------
// x_dbl[t, e] = sum_d xi[t,d] * W_x[e,d],  e in [0,33).  Block per token.
// ---------------------------------------------------------------------------
__launch_bounds__(256)
__global__ void xdbl_kernel(const float* __restrict__ xi,
                            const float* __restrict__ W_x,
                            float* __restrict__ xdbl)
{
    __shared__ float row[D_INNER];
    const int t = blockIdx.x;
    const float* xr = xi + (size_t)t * D_INNER;
    for (int i = threadIdx.x; i < D_INNER; i += 256) row[i] = xr[i];
    __syncthreads();

    const int wave = threadIdx.x >> 6;
    const int lane = threadIdx.x & 63;
    for (int e = wave; e < NDBL; e += 4) {
        const float* wr = W_x + (size_t)e * D_INNER;
        float s = 0.f;
        for (int i = lane; i < D_INNER; i += 64) s = fmaf(row[i], wr[i], s);
#pragma unroll
        for (int off = 32; off; off >>= 1) s += __shfl_xor(s, off);
        if (lane == 0) xdbl[(size_t)t * NDBL + e] = s;
    }
}

// ---------------------------------------------------------------------------
// Chunked scan pass 1: per-chunk local scan from h=0; record prod(dA), h_end.
// ---------------------------------------------------------------------------
__launch_bounds__(256)
__global__ void scan_pass1(const float* __restrict__ xdbl,
                           const float* __restrict__ xi,
                           const float* __restrict__ W_dt,
                           const float* __restrict__ b_dt,
                           const float* __restrict__ A_log,
                           float* __restrict__ aprod,
                           float* __restrict__ hloc)
{
    const int tid  = threadIdx.x;
    const int n    = tid & 15;
    const int dloc = tid >> 4;
    const int d    = blockIdx.x * 16 + dloc;
    const int c    = blockIdx.y;
    const int b    = blockIdx.z;

    const float A   = -__expf(A_log[(size_t)d * D_STATE + n]);
    const float wdt = W_dt[d], bdt = b_dt[d];

    const int l0 = c * CHUNK;
    const float* xd = xdbl + ((size_t)b * SEQ + l0) * NDBL;
    const float* xp = xi + ((size_t)b * SEQ + l0) * D_INNER + d;

    float h = 0.f, ap = 1.f;
#pragma unroll 4
    for (int l = 0; l < CHUNK; ++l) {
        float raw = xd[0];
        float Bv  = xd[1 + n];
        float xv  = xp[0];
        xd += NDBL; xp += D_INNER;
        float dtv = softplus_fast(fmaf(raw, wdt, bdt));
        float dA  = __expf(dtv * A);
        h  = fmaf(dA, h, (dtv * Bv) * xv);
        ap *= dA;
    }
    size_t idx = ((((size_t)b * NCHUNK + c) * D_INNER + d) << 4) + n;
    aprod[idx] = ap;
    hloc[idx]  = h;
}

// ---------------------------------------------------------------------------
// Chunked scan combine: serial over 32 chunk summaries; h_start per chunk.
// ---------------------------------------------------------------------------
__global__ void scan_combine(const float* __restrict__ aprod,
                             const float* __restrict__ hloc,
                             float* __restrict__ hstart)
{
    int idx = blockIdx.x * blockDim.x + threadIdx.x;  // b*32768 + d*16 + n
    int b  = idx >> 15;
    int dn = idx & 32767;
    float hs = 0.f;
#pragma unroll
    for (int c = 0; c < NCHUNK; ++c) {
        size_t s = (((size_t)b * NCHUNK + c) << 15) + dn;
        hstart[s] = hs;
        hs = fmaf(aprod[s], hs, hloc[s]);
    }
}

// ---------------------------------------------------------------------------
// Chunked scan pass 2: rescan from h_start; emit gated y in-place into xi.
// ---------------------------------------------------------------------------
__launch_bounds__(256)
__global__ void scan_pass2(const float* __restrict__ xdbl,
                           float* __restrict__ xi,
                           const float* __restrict__ xz,
                           const float* __restrict__ W_dt,
                           const float* __restrict__ b_dt,
                           const float* __restrict__ A_log,
                           const float* __restrict__ Dvec,
                           const float* __restrict__ hstart)
{
    const int tid  = threadIdx.x;
    const int n    = tid & 15;
    const int dloc = tid >> 4;
    const int d    = blockIdx.x * 16 + dloc;
    const int c    = blockIdx.y;
    const int b    = blockIdx.z;

    const float A   = -__expf(A_log[(size_t)d * D_STATE + n]);
    const float wdt = W_dt[d], bdt = b_dt[d], Dd = Dvec[d];

    const int l0 = c * CHUNK;
    const float* xd = xdbl + ((size_t)b * SEQ + l0) * NDBL;
    float*       xp = xi + ((size_t)b * SEQ + l0) * D_INNER + d;
    const float* zp = xz + ((size_t)b * SEQ + l0) * NXZ + D_INNER + d;

    size_t sidx = ((((size_t)b * NCHUNK + c) * D_INNER + d) << 4) + n;
    float h = hstart[sidx];

#pragma unroll 4
    for (int l = 0; l < CHUNK; ++l) {
        float raw = xd[0];
        float Bv  = xd[1 + n];
        float Cv  = xd[1 + D_STATE + n];
        float xv  = xp[0];
        float dtv = softplus_fast(fmaf(raw, wdt, bdt));
        float dA  = __expf(dtv * A);
        h = fmaf(dA, h, (dtv * Bv) * xv);

        float p = h * Cv;
        p += __shfl_xor(p, 1);
        p += __shfl_xor(p, 2);
        p += __shfl_xor(p, 4);
        p += __shfl_xor(p, 8);

        if (n == 0) {
            float y  = p + Dd * xv;
            float zv = zp[0];
            xp[0] = y * silu_fast(zv);
        }
        xd += NDBL; xp += D_INNER; zp += NXZ;
    }
}

// ---------------------------------------------------------------------------
extern "C" void kernel_launch(void* const* d_in, const int* in_sizes, int n_in,
                              void* d_out, int out_size, void* d_ws, size_t ws_size,
                              hipStream_t stream)
{
    (void)in_sizes; (void)n_in; (void)out_size; (void)ws_size;

    const float* x      = (const float*)d_in[0];
    const float* W_in   = (const float*)d_in[1];
    const float* conv_w = (const float*)d_in[2];
    const float* conv_b = (const float*)d_in[3];
    const float* W_x    = (const float*)d_in[4];
    const float* W_dt   = (const float*)d_in[5];
    const float* b_dt   = (const float*)d_in[6];
    const float* A_log  = (const float*)d_in[7];
    const float* Dvec   = (const float*)d_in[8];
    const float* W_out  = (const float*)d_in[9];
    float* out = (float*)d_out;

    // ---- workspace map ----
    float* xz   = (float*)d_ws;                    // 4096x4096 f32 (64MB)
    float* xi   = xz + (size_t)NTOK * NXZ;         // 4096x2048 f32 (32MB)
    float* xdbl = xi + (size_t)NTOK * D_INNER;     // 4096x33 f32
    float* R    = xdbl + (size_t)NTOK * NDBL;      // 32MB shared region

    // phase-1 occupants of R: hi/lo splits of x and W_in
    short* x_hi   = (short*)R;
    short* x_lo   = x_hi + (size_t)NTOK * D_MODEL;
    short* Win_hi = x_lo + (size_t)NTOK * D_MODEL;
    short* Win_lo = Win_hi + (size_t)NXZ * D_MODEL;
    // phase-2 occupants of R: scan buffers
    float* aprod  = R;
    float* hloc   = aprod + (size_t)BATCH * NCHUNK * D_INNER * 16;
    float* hstart = hloc + (size_t)BATCH * NCHUNK * D_INNER * 16;
    // phase-3 occupants of xz region (z consumed by pass2): y / W_out splits
    short* y_hi   = (short*)xz;
    short* y_lo   = y_hi + (size_t)NTOK * D_INNER;
    short* Wou_hi = y_lo + (size_t)NTOK * D_INNER;
    short* Wou_lo = Wou_hi + (size_t)D_MODEL * D_INNER;

    // 0) split x and W_in to bf16 hi/lo
    split_kernel<<<(NTOK * D_MODEL / 4 + 255) / 256, 256, 0, stream>>>(x, x_hi, x_lo, NTOK * D_MODEL / 4);
    split_kernel<<<(NXZ * D_MODEL / 4 + 255) / 256, 256, 0, stream>>>(W_in, Win_hi, Win_lo, NXZ * D_MODEL / 4);

    // 1) xz = x @ W_in^T   (M=4096, N=4096, K=1024)
    {
        dim3 grid(NXZ / 128, NTOK / 128);
        mfma_gemm_split<<<grid, 256, 0, stream>>>(x_hi, x_lo, Win_hi, Win_lo, xz, NTOK, NXZ, D_MODEL);
    }
    // 2) depthwise conv + SiLU -> xi
    {
        int total = NTOK * D_INNER;
        conv_silu_kernel<<<(total + 255) / 256, 256, 0, stream>>>(xz, conv_w, conv_b, xi);
    }
    // 3) x_dbl = xi @ W_x^T  (N=33)
    xdbl_kernel<<<NTOK, 256, 0, stream>>>(xi, W_x, xdbl);

    // 4) chunked selective scan
    {
        dim3 grid(D_INNER / 16, NCHUNK, BATCH);
        scan_pass1<<<grid, 256, 0, stream>>>(xdbl, xi, W_dt, b_dt, A_log, aprod, hloc);
        scan_combine<<<(BATCH * D_INNER * 16) / 256, 256, 0, stream>>>(aprod, hloc, hstart);
        scan_pass2<<<grid, 256, 0, stream>>>(xdbl, xi, xz, W_dt, b_dt, A_log, Dvec, hstart);
    }
    // 5) split y (=xi) and W_out, then out = y @ W_out^T  (M=4096, N=1024, K=2048)
    split_kernel<<<(NTOK * D_INNER / 4 + 255) / 256, 256, 0, stream>>>(xi, y_hi, y_lo, NTOK * D_INNER / 4);
    split_kernel<<<(D_MODEL * D_INNER / 4 + 255) / 256, 256, 0, stream>>>(W_out, Wou_hi, Wou_lo, D_MODEL * D_INNER / 4);
    {
        dim3 grid(D_MODEL / 128, NTOK / 128);
        mfma_gemm_split<<<grid, 256, 0, stream>>>(y_hi, y_lo, Wou_hi, Wou_lo, out, NTOK, D_MODEL, D_INNER);
    }
}

// Round 7
// 656.660 us; speedup vs baseline: 4.6441x; 1.3356x over previous
//
#include <hip/hip_runtime.h>
#include <hip/hip_bf16.h>

#define D_MODEL 1024
#define D_STATE 16
#define D_CONV  4
#define D_INNER 2048
#define BATCH   2
#define SEQ     2048
#define NTOK    (BATCH * SEQ)      // 4096
#define NXZ     (2 * D_INNER)      // 4096
#define NDBL    (2 * D_STATE + 1)  // 33
#define XROW    40                 // padded x_dbl row: [dt,_,_,_, B0..15, C0..15, pad4]
#define CHUNK   32
#define NCHUNK  (SEQ / CHUNK)      // 64

typedef __attribute__((ext_vector_type(8))) short bf16x8;
typedef __attribute__((ext_vector_type(4))) float f32x4;

__device__ __forceinline__ float silu_fast(float x) {
    return x / (1.0f + __expf(-x));
}
__device__ __forceinline__ float softplus_fast(float x) {
    float r = __logf(1.0f + __expf(x));
    return (x > 20.f) ? x : r;
}
__device__ __forceinline__ short f2bf(float f) {
    __hip_bfloat16 h = __float2bfloat16(f);
    return __builtin_bit_cast(short, h);
}
__device__ __forceinline__ float bf2f(short s) {
    return __bfloat162float(__builtin_bit_cast(__hip_bfloat16, s));
}
__device__ __forceinline__ void gload_lds16(const void* g, void* l) {
    __builtin_amdgcn_global_load_lds(
        (const __attribute__((address_space(1))) void*)g,
        (__attribute__((address_space(3))) void*)l, 16, 0, 0);
}

// ---------------------------------------------------------------------------
// Split fp32 -> (hi, lo) bf16 pair.  n4 = count/4.
// ---------------------------------------------------------------------------
__global__ void split_kernel(const float* __restrict__ in, short* __restrict__ hi,
                             short* __restrict__ lo, int n4)
{
    int i = blockIdx.x * blockDim.x + threadIdx.x;
    if (i >= n4) return;
    float4 v = ((const float4*)in)[i];
    short4 h, l;
    h.x = f2bf(v.x); l.x = f2bf(v.x - bf2f(h.x));
    h.y = f2bf(v.y); l.y = f2bf(v.y - bf2f(h.y));
    h.z = f2bf(v.z); l.z = f2bf(v.z - bf2f(h.z));
    h.w = f2bf(v.w); l.w = f2bf(v.w - bf2f(h.w));
    ((short4*)hi)[i] = h;
    ((short4*)lo)[i] = l;
}

// ---------------------------------------------------------------------------
// Split-bf16 MFMA GEMM: C[M,N] = A[M,K] * B[N,K]^T  (fp32-accurate via hi/lo).
// ---------------------------------------------------------------------------
__launch_bounds__(256, 2)
__global__ void mfma_gemm_split(const short* __restrict__ Ahi, const short* __restrict__ Alo,
                                const short* __restrict__ Bhi, const short* __restrict__ Blo,
                                float* __restrict__ C, int M, int N, int K)
{
    __shared__ short sAh[4096], sAl[4096], sBh[4096], sBl[4096];
    const int tid  = threadIdx.x;
    const int lane = tid & 63;
    const int wave = tid >> 6;
    const int bm = blockIdx.y, bn = blockIdx.x;
    const int wm = wave >> 1, wn = wave & 1;

    const int r0a = bm * 128, r0b = bn * 128;

    f32x4 acc[4][4] = {};

    for (int k0 = 0; k0 < K; k0 += 32) {
        __syncthreads();
#pragma unroll
        for (int i = 0; i < 2; ++i) {
            const int off = i * 4096 + tid * 16;
            const int g   = off >> 11;
            const int row = (off >> 4) & 127;
            const size_t ea = (size_t)(r0a + row) * K + k0 + g * 8;
            const size_t eb = (size_t)(r0b + row) * K + k0 + g * 8;
            char* la = (char*)sAh + i * 4096 + wave * 1024;
            gload_lds16(Ahi + ea, la);
            gload_lds16(Alo + ea, (char*)sAl + i * 4096 + wave * 1024);
            gload_lds16(Bhi + eb, (char*)sBh + i * 4096 + wave * 1024);
            gload_lds16(Blo + eb, (char*)sBl + i * 4096 + wave * 1024);
        }
        __syncthreads();

        const int g = lane >> 4;
        bf16x8 ah[4], al[4], bh[4], bl[4];
#pragma unroll
        for (int m = 0; m < 4; ++m) {
            const int rowA = wm * 64 + m * 16 + (lane & 15);
            const int rowB = wn * 64 + m * 16 + (lane & 15);
            ah[m] = ((const bf16x8*)sAh)[g * 128 + rowA];
            al[m] = ((const bf16x8*)sAl)[g * 128 + rowA];
            bh[m] = ((const bf16x8*)sBh)[g * 128 + rowB];
            bl[m] = ((const bf16x8*)sBl)[g * 128 + rowB];
        }
#pragma unroll
        for (int m = 0; m < 4; ++m)
#pragma unroll
            for (int n = 0; n < 4; ++n) {
                acc[m][n] = __builtin_amdgcn_mfma_f32_16x16x32_bf16(ah[m], bh[n], acc[m][n], 0, 0, 0);
                acc[m][n] = __builtin_amdgcn_mfma_f32_16x16x32_bf16(ah[m], bl[n], acc[m][n], 0, 0, 0);
                acc[m][n] = __builtin_amdgcn_mfma_f32_16x16x32_bf16(al[m], bh[n], acc[m][n], 0, 0, 0);
            }
    }

#pragma unroll
    for (int m = 0; m < 4; ++m) {
        const int row = bm * 128 + wm * 64 + m * 16 + ((lane >> 4) << 2);
#pragma unroll
        for (int n = 0; n < 4; ++n) {
            const int col = bn * 128 + wn * 64 + n * 16 + (lane & 15);
#pragma unroll
            for (int r = 0; r < 4; ++r)
                C[(size_t)(row + r) * N + col] = acc[m][n][r];
        }
    }
}

// ---------------------------------------------------------------------------
// Depthwise causal conv (k=4) + bias + SiLU (fast).
// ---------------------------------------------------------------------------
__global__ void conv_silu_kernel(const float* __restrict__ xz,
                                 const float* __restrict__ conv_w,
                                 const float* __restrict__ conv_b,
                                 float* __restrict__ xi)
{
    int idx = blockIdx.x * blockDim.x + threadIdx.x;
    if (idx >= NTOK * D_INNER) return;
    int d = idx % D_INNER;
    int t = idx / D_INNER;
    int l = t % SEQ;
    int b = t / SEQ;

    float w0 = conv_w[d * 4 + 0], w1 = conv_w[d * 4 + 1];
    float w2 = conv_w[d * 4 + 2], w3 = conv_w[d * 4 + 3];

    const float* base = xz + ((size_t)b * SEQ) * NXZ + d;
    float acc = conv_b[d];
    if (l >= 3) acc = fmaf(w0, base[(size_t)(l - 3) * NXZ], acc);
    if (l >= 2) acc = fmaf(w1, base[(size_t)(l - 2) * NXZ], acc);
    if (l >= 1) acc = fmaf(w2, base[(size_t)(l - 1) * NXZ], acc);
    acc = fmaf(w3, base[(size_t)l * NXZ], acc);
    xi[idx] = silu_fast(acc);
}

// ---------------------------------------------------------------------------
// x_dbl[t, slot] padded layout: slot 0 = dt_raw, slots 4..19 = B, 20..35 = C.
// ---------------------------------------------------------------------------
__launch_bounds__(256)
__global__ void xdbl_kernel(const float* __restrict__ xi,
                            const float* __restrict__ W_x,
                            float* __restrict__ xdbl)
{
    __shared__ float row[D_INNER];
    const int t = blockIdx.x;
    const float* xr = xi + (size_t)t * D_INNER;
    for (int i = threadIdx.x; i < D_INNER; i += 256) row[i] = xr[i];
    __syncthreads();

    const int wave = threadIdx.x >> 6;
    const int lane = threadIdx.x & 63;
    for (int e = wave; e < NDBL; e += 4) {
        const float* wr = W_x + (size_t)e * D_INNER;
        float s = 0.f;
        for (int i = lane; i < D_INNER; i += 64) s = fmaf(row[i], wr[i], s);
#pragma unroll
        for (int off = 32; off; off >>= 1) s += __shfl_xor(s, off);
        if (lane == 0) xdbl[(size_t)t * XROW + (e == 0 ? 0 : e + 3)] = s;
    }
}

// ---------------------------------------------------------------------------
// Chunked scan pass 1: thread per (b, d, chunk); all 16 n-states in registers.
// Writes prod(dA)[16] and local end-state h[16] per thread.
// ---------------------------------------------------------------------------
__launch_bounds__(256)
__global__ void scan_pass1(const float* __restrict__ xdbl,
                           const float* __restrict__ xi,
                           const float* __restrict__ W_dt,
                           const float* __restrict__ b_dt,
                           const float* __restrict__ A_log,
                           float* __restrict__ aprod,
                           float* __restrict__ hloc)
{
    const int d = blockIdx.x * 256 + threadIdx.x;
    const int c = blockIdx.y;
    const int b = blockIdx.z;

    float A[16];
    {
        const float4* ar = (const float4*)(A_log + (size_t)d * 16);
#pragma unroll
        for (int q = 0; q < 4; ++q) {
            float4 v = ar[q];
            A[q * 4 + 0] = -__expf(v.x);
            A[q * 4 + 1] = -__expf(v.y);
            A[q * 4 + 2] = -__expf(v.z);
            A[q * 4 + 3] = -__expf(v.w);
        }
    }
    const float wdt = W_dt[d], bdt = b_dt[d];

    const float* xd = xdbl + ((size_t)b * SEQ + c * CHUNK) * XROW;
    const float* xp = xi + ((size_t)b * SEQ + c * CHUNK) * D_INNER + d;

    float h[16], ap[16], Bv[16];
#pragma unroll
    for (int n = 0; n < 16; ++n) { h[n] = 0.f; ap[n] = 1.f; }

    for (int l = 0; l < CHUNK; ++l) {
        float raw = xd[0];
#pragma unroll
        for (int q = 0; q < 4; ++q) {
            float4 v = *(const float4*)(xd + 4 + q * 4);
            Bv[q * 4 + 0] = v.x; Bv[q * 4 + 1] = v.y;
            Bv[q * 4 + 2] = v.z; Bv[q * 4 + 3] = v.w;
        }
        float xv = xp[0];
        float dtv = softplus_fast(fmaf(raw, wdt, bdt));
        float dtx = dtv * xv;
#pragma unroll
        for (int n = 0; n < 16; ++n) {
            float e = __expf(dtv * A[n]);
            h[n]  = fmaf(e, h[n], Bv[n] * dtx);
            ap[n] *= e;
        }
        xd += XROW; xp += D_INNER;
    }

    size_t s = (((size_t)b * NCHUNK + c) * D_INNER + d) * 16;
#pragma unroll
    for (int q = 0; q < 4; ++q) {
        *(float4*)(aprod + s + q * 4) = make_float4(ap[q*4], ap[q*4+1], ap[q*4+2], ap[q*4+3]);
        *(float4*)(hloc  + s + q * 4) = make_float4(h[q*4],  h[q*4+1],  h[q*4+2],  h[q*4+3]);
    }
}

// ---------------------------------------------------------------------------
// Chunked scan combine: serial over NCHUNK chunk summaries; writes h_start
// IN-PLACE into aprod.
// ---------------------------------------------------------------------------
__global__ void scan_combine(float* __restrict__ aprod,
                             const float* __restrict__ hloc)
{
    int idx = blockIdx.x * blockDim.x + threadIdx.x;  // b*32768 + d*16 + n
    int b  = idx >> 15;
    int dn = idx & 32767;
    float hs = 0.f;
#pragma unroll
    for (int c = 0; c < NCHUNK; ++c) {
        size_t s = (((size_t)b * NCHUNK + c) << 15) + dn;
        float ap = aprod[s];
        float hl = hloc[s];
        aprod[s] = hs;                 // h_start for this chunk
        hs = fmaf(ap, hs, hl);
    }
}

// ---------------------------------------------------------------------------
// Chunked scan pass 2: thread per (b, d, chunk); rescan from h_start; emit
// gated y in-place into xi.  No shuffles: C-dot is 16 in-register FMAs.
// ---------------------------------------------------------------------------
__launch_bounds__(256)
__global__ void scan_pass2(const float* __restrict__ xdbl,
                           float* __restrict__ xi,
                           const float* __restrict__ xz,
                           const float* __restrict__ W_dt,
                           const float* __restrict__ b_dt,
                           const float* __restrict__ A_log,
                           const float* __restrict__ Dvec,
                           const float* __restrict__ hstart)
{
    const int d = blockIdx.x * 256 + threadIdx.x;
    const int c = blockIdx.y;
    const int b = blockIdx.z;

    float A[16];
    {
        const float4* ar = (const float4*)(A_log + (size_t)d * 16);
#pragma unroll
        for (int q = 0; q < 4; ++q) {
            float4 v = ar[q];
            A[q * 4 + 0] = -__expf(v.x);
            A[q * 4 + 1] = -__expf(v.y);
            A[q * 4 + 2] = -__expf(v.z);
            A[q * 4 + 3] = -__expf(v.w);
        }
    }
    const float wdt = W_dt[d], bdt = b_dt[d], Dd = Dvec[d];

    const float* xd = xdbl + ((size_t)b * SEQ + c * CHUNK) * XROW;
    float*       xp = xi + ((size_t)b * SEQ + c * CHUNK) * D_INNER + d;
    const float* zp = xz + ((size_t)b * SEQ + c * CHUNK) * NXZ + D_INNER + d;

    float h[16], Bv[16], Cv[16];
    {
        size_t s = (((size_t)b * NCHUNK + c) * D_INNER + d) * 16;
#pragma unroll
        for (int q = 0; q < 4; ++q) {
            float4 v = *(const float4*)(hstart + s + q * 4);
            h[q * 4 + 0] = v.x; h[q * 4 + 1] = v.y;
            h[q * 4 + 2] = v.z; h[q * 4 + 3] = v.w;
        }
    }

    for (int l = 0; l < CHUNK; ++l) {
        float raw = xd[0];
#pragma unroll
        for (int q = 0; q < 4; ++q) {
            float4 v = *(const float4*)(xd + 4 + q * 4);
            Bv[q * 4 + 0] = v.x; Bv[q * 4 + 1] = v.y;
            Bv[q * 4 + 2] = v.z; Bv[q * 4 + 3] = v.w;
            float4 w = *(const float4*)(xd + 20 + q * 4);
            Cv[q * 4 + 0] = w.x; Cv[q * 4 + 1] = w.y;
            Cv[q * 4 + 2] = w.z; Cv[q * 4 + 3] = w.w;
        }
        float xv = xp[0];
        float zv = zp[0];
        float dtv = softplus_fast(fmaf(raw, wdt, bdt));
        float dtx = dtv * xv;

        float p0 = 0.f, p1 = 0.f, p2 = 0.f, p3 = 0.f;
#pragma unroll
        for (int q = 0; q < 4; ++q) {
            float e0 = __expf(dtv * A[q*4+0]);
            float e1 = __expf(dtv * A[q*4+1]);
            float e2 = __expf(dtv * A[q*4+2]);
            float e3 = __expf(dtv * A[q*4+3]);
            h[q*4+0] = fmaf(e0, h[q*4+0], Bv[q*4+0] * dtx);
            h[q*4+1] = fmaf(e1, h[q*4+1], Bv[q*4+1] * dtx);
            h[q*4+2] = fmaf(e2, h[q*4+2], Bv[q*4+2] * dtx);
            h[q*4+3] = fmaf(e3, h[q*4+3], Bv[q*4+3] * dtx);
            p0 = fmaf(h[q*4+0], Cv[q*4+0], p0);
            p1 = fmaf(h[q*4+1], Cv[q*4+1], p1);
            p2 = fmaf(h[q*4+2], Cv[q*4+2], p2);
            p3 = fmaf(h[q*4+3], Cv[q*4+3], p3);
        }
        float y = (p0 + p1) + (p2 + p3) + Dd * xv;
        xp[0] = y * silu_fast(zv);

        xd += XROW; xp += D_INNER; zp += NXZ;
    }
}

// ---------------------------------------------------------------------------
extern "C" void kernel_launch(void* const* d_in, const int* in_sizes, int n_in,
                              void* d_out, int out_size, void* d_ws, size_t ws_size,
                              hipStream_t stream)
{
    (void)in_sizes; (void)n_in; (void)out_size; (void)ws_size;

    const float* x      = (const float*)d_in[0];
    const float* W_in   = (const float*)d_in[1];
    const float* conv_w = (const float*)d_in[2];
    const float* conv_b = (const float*)d_in[3];
    const float* W_x    = (const float*)d_in[4];
    const float* W_dt   = (const float*)d_in[5];
    const float* b_dt   = (const float*)d_in[6];
    const float* A_log  = (const float*)d_in[7];
    const float* Dvec   = (const float*)d_in[8];
    const float* W_out  = (const float*)d_in[9];
    float* out = (float*)d_out;

    // ---- workspace map ----
    float* xz   = (float*)d_ws;                    // 4096x4096 f32 (64MB)
    float* xi   = xz + (size_t)NTOK * NXZ;         // 4096x2048 f32 (32MB)
    float* xdbl = xi + (size_t)NTOK * D_INNER;     // 4096x40 f32 (padded)
    float* R    = xdbl + (size_t)NTOK * XROW;      // shared region

    // phase-1 occupants of R: hi/lo splits of x and W_in (33.5MB)
    short* x_hi   = (short*)R;
    short* x_lo   = x_hi + (size_t)NTOK * D_MODEL;
    short* Win_hi = x_lo + (size_t)NTOK * D_MODEL;
    short* Win_lo = Win_hi + (size_t)NXZ * D_MODEL;
    // phase-2 occupants of R: scan buffers (aprod doubles as hstart; 33.5MB)
    float* aprod  = R;
    float* hloc   = aprod + (size_t)BATCH * NCHUNK * D_INNER * 16;
    // phase-3 occupants of xz region (z consumed by pass2): y / W_out splits
    short* y_hi   = (short*)xz;
    short* y_lo   = y_hi + (size_t)NTOK * D_INNER;
    short* Wou_hi = y_lo + (size_t)NTOK * D_INNER;
    short* Wou_lo = Wou_hi + (size_t)D_MODEL * D_INNER;

    // 0) split x and W_in to bf16 hi/lo
    split_kernel<<<(NTOK * D_MODEL / 4 + 255) / 256, 256, 0, stream>>>(x, x_hi, x_lo, NTOK * D_MODEL / 4);
    split_kernel<<<(NXZ * D_MODEL / 4 + 255) / 256, 256, 0, stream>>>(W_in, Win_hi, Win_lo, NXZ * D_MODEL / 4);

    // 1) xz = x @ W_in^T   (M=4096, N=4096, K=1024)
    {
        dim3 grid(NXZ / 128, NTOK / 128);
        mfma_gemm_split<<<grid, 256, 0, stream>>>(x_hi, x_lo, Win_hi, Win_lo, xz, NTOK, NXZ, D_MODEL);
    }
    // 2) depthwise conv + SiLU -> xi
    {
        int total = NTOK * D_INNER;
        conv_silu_kernel<<<(total + 255) / 256, 256, 0, stream>>>(xz, conv_w, conv_b, xi);
    }
    // 3) x_dbl = xi @ W_x^T  (padded rows)
    xdbl_kernel<<<NTOK, 256, 0, stream>>>(xi, W_x, xdbl);

    // 4) chunked selective scan (register-resident n-states)
    {
        dim3 grid(D_INNER / 256, NCHUNK, BATCH);
        scan_pass1<<<grid, 256, 0, stream>>>(xdbl, xi, W_dt, b_dt, A_log, aprod, hloc);
        scan_combine<<<(BATCH * D_INNER * 16) / 256, 256, 0, stream>>>(aprod, hloc);
        scan_pass2<<<grid, 256, 0, stream>>>(xdbl, xi, xz, W_dt, b_dt, A_log, Dvec, aprod);
    }
    // 5) split y (=xi) and W_out, then out = y @ W_out^T  (M=4096, N=1024, K=2048)
    split_kernel<<<(NTOK * D_INNER / 4 + 255) / 256, 256, 0, stream>>>(xi, y_hi, y_lo, NTOK * D_INNER / 4);
    split_kernel<<<(D_MODEL * D_INNER / 4 + 255) / 256, 256, 0, stream>>>(W_out, Wou_hi, Wou_lo, D_MODEL * D_INNER / 4);
    {
        dim3 grid(D_MODEL / 128, NTOK / 128);
        mfma_gemm_split<<<grid, 256, 0, stream>>>(y_hi, y_lo, Wou_hi, Wou_lo, out, NTOK, D_MODEL, D_INNER);
    }
}

// Round 8
// 595.677 us; speedup vs baseline: 5.1196x; 1.1024x over previous
//
#include <hip/hip_runtime.h>
#include <hip/hip_bf16.h>

#define D_MODEL 1024
#define D_STATE 16
#define D_CONV  4
#define D_INNER 2048
#define BATCH   2
#define SEQ     2048
#define NTOK    (BATCH * SEQ)      // 4096
#define NXZ     (2 * D_INNER)      // 4096
#define NDBL    (2 * D_STATE + 1)  // 33
#define XROW    40                 // padded x_dbl row: [dt,_,_,_, B0..15, C0..15, pad4]
#define CHUNK   32
#define NCHUNK  (SEQ / CHUNK)      // 64
#define XT      4                  // tokens per xdbl block

typedef __attribute__((ext_vector_type(8))) short bf16x8;
typedef __attribute__((ext_vector_type(4))) float f32x4;

__device__ __forceinline__ float silu_fast(float x) {
    return x / (1.0f + __expf(-x));
}
__device__ __forceinline__ float softplus_fast(float x) {
    float r = __logf(1.0f + __expf(x));
    return (x > 20.f) ? x : r;
}
__device__ __forceinline__ short f2bf(float f) {
    __hip_bfloat16 h = __float2bfloat16(f);
    return __builtin_bit_cast(short, h);
}
__device__ __forceinline__ float bf2f(short s) {
    return __bfloat162float(__builtin_bit_cast(__hip_bfloat16, s));
}
__device__ __forceinline__ void gload_lds16(const void* g, void* l) {
    __builtin_amdgcn_global_load_lds(
        (const __attribute__((address_space(1))) void*)g,
        (__attribute__((address_space(3))) void*)l, 16, 0, 0);
}

// ---------------------------------------------------------------------------
// Split fp32 -> (hi, lo) bf16 pair.  n4 = count/4.
// ---------------------------------------------------------------------------
__global__ void split_kernel(const float* __restrict__ in, short* __restrict__ hi,
                             short* __restrict__ lo, int n4)
{
    int i = blockIdx.x * blockDim.x + threadIdx.x;
    if (i >= n4) return;
    float4 v = ((const float4*)in)[i];
    short4 h, l;
    h.x = f2bf(v.x); l.x = f2bf(v.x - bf2f(h.x));
    h.y = f2bf(v.y); l.y = f2bf(v.y - bf2f(h.y));
    h.z = f2bf(v.z); l.z = f2bf(v.z - bf2f(h.z));
    h.w = f2bf(v.w); l.w = f2bf(v.w - bf2f(h.w));
    ((short4*)hi)[i] = h;
    ((short4*)lo)[i] = l;
}

// ---------------------------------------------------------------------------
// Split-bf16 MFMA GEMM: C[M,N] = A[M,K] * B[N,K]^T  (fp32-accurate via hi/lo).
// 128x128 tile, BK=32, 4 waves.  2-phase single-buffer pipeline: MFMA of
// step k overlaps the global_load_lds of step k+1 (vmcnt drain happens at
// the next iteration's first barrier, hidden under 48 MFMAs x 12 waves/CU).
// ---------------------------------------------------------------------------
__launch_bounds__(256, 3)
__global__ void mfma_gemm_split(const short* __restrict__ Ahi, const short* __restrict__ Alo,
                                const short* __restrict__ Bhi, const short* __restrict__ Blo,
                                float* __restrict__ C, int M, int N, int K)
{
    __shared__ short sAh[4096], sAl[4096], sBh[4096], sBl[4096];
    const int tid  = threadIdx.x;
    const int lane = tid & 63;
    const int wave = tid >> 6;
    const int bm = blockIdx.y, bn = blockIdx.x;
    const int wm = wave >> 1, wn = wave & 1;

    const int r0a = bm * 128, r0b = bn * 128;

    auto stage = [&](int k0) {
#pragma unroll
        for (int i = 0; i < 2; ++i) {
            const int off = i * 4096 + tid * 16;   // LDS byte offset this lane fills
            const int g   = off >> 11;             // granule 0..3
            const int row = (off >> 4) & 127;      // tile row 0..127
            const size_t ea = (size_t)(r0a + row) * K + k0 + g * 8;
            const size_t eb = (size_t)(r0b + row) * K + k0 + g * 8;
            gload_lds16(Ahi + ea, (char*)sAh + i * 4096 + wave * 1024);
            gload_lds16(Alo + ea, (char*)sAl + i * 4096 + wave * 1024);
            gload_lds16(Bhi + eb, (char*)sBh + i * 4096 + wave * 1024);
            gload_lds16(Blo + eb, (char*)sBl + i * 4096 + wave * 1024);
        }
    };

    f32x4 acc[4][4] = {};

    stage(0);
    for (int k0 = 0; k0 < K; k0 += 32) {
        __syncthreads();   // staged data for k0 visible (drains vmcnt)

        const int g = lane >> 4;
        bf16x8 ah[4], al[4], bh[4], bl[4];
#pragma unroll
        for (int m = 0; m < 4; ++m) {
            const int rowA = wm * 64 + m * 16 + (lane & 15);
            const int rowB = wn * 64 + m * 16 + (lane & 15);
            ah[m] = ((const bf16x8*)sAh)[g * 128 + rowA];
            al[m] = ((const bf16x8*)sAl)[g * 128 + rowA];
            bh[m] = ((const bf16x8*)sBh)[g * 128 + rowB];
            bl[m] = ((const bf16x8*)sBl)[g * 128 + rowB];
        }
        __syncthreads();   // frags in regs (lgkmcnt drained); LDS free to overwrite

        if (k0 + 32 < K) stage(k0 + 32);   // issue next staging; MFMAs hide it

#pragma unroll
        for (int m = 0; m < 4; ++m)
#pragma unroll
            for (int n = 0; n < 4; ++n) {
                acc[m][n] = __builtin_amdgcn_mfma_f32_16x16x32_bf16(ah[m], bh[n], acc[m][n], 0, 0, 0);
                acc[m][n] = __builtin_amdgcn_mfma_f32_16x16x32_bf16(ah[m], bl[n], acc[m][n], 0, 0, 0);
                acc[m][n] = __builtin_amdgcn_mfma_f32_16x16x32_bf16(al[m], bh[n], acc[m][n], 0, 0, 0);
            }
    }

    // epilogue: C/D layout col=lane&15, row=(lane>>4)*4+reg
#pragma unroll
    for (int m = 0; m < 4; ++m) {
        const int row = bm * 128 + wm * 64 + m * 16 + ((lane >> 4) << 2);
#pragma unroll
        for (int n = 0; n < 4; ++n) {
            const int col = bn * 128 + wn * 64 + n * 16 + (lane & 15);
#pragma unroll
            for (int r = 0; r < 4; ++r)
                C[(size_t)(row + r) * N + col] = acc[m][n][r];
        }
    }
}

// ---------------------------------------------------------------------------
// Depthwise causal conv (k=4) + bias + SiLU (fast).
// ---------------------------------------------------------------------------
__global__ void conv_silu_kernel(const float* __restrict__ xz,
                                 const float* __restrict__ conv_w,
                                 const float* __restrict__ conv_b,
                                 float* __restrict__ xi)
{
    int idx = blockIdx.x * blockDim.x + threadIdx.x;
    if (idx >= NTOK * D_INNER) return;
    int d = idx % D_INNER;
    int t = idx / D_INNER;
    int l = t % SEQ;
    int b = t / SEQ;

    float w0 = conv_w[d * 4 + 0], w1 = conv_w[d * 4 + 1];
    float w2 = conv_w[d * 4 + 2], w3 = conv_w[d * 4 + 3];

    const float* base = xz + ((size_t)b * SEQ) * NXZ + d;
    float acc = conv_b[d];
    if (l >= 3) acc = fmaf(w0, base[(size_t)(l - 3) * NXZ], acc);
    if (l >= 2) acc = fmaf(w1, base[(size_t)(l - 2) * NXZ], acc);
    if (l >= 1) acc = fmaf(w2, base[(size_t)(l - 1) * NXZ], acc);
    acc = fmaf(w3, base[(size_t)l * NXZ], acc);
    xi[idx] = silu_fast(acc);
}

// ---------------------------------------------------------------------------
// x_dbl: XT tokens per block; one W_x read feeds XT FMA streams (L2 /XT).
// Padded row layout: slot 0 = dt_raw, 4..19 = B, 20..35 = C.
// ---------------------------------------------------------------------------
__launch_bounds__(256)
__global__ void xdbl_kernel(const float* __restrict__ xi,
                            const float* __restrict__ W_x,
                            float* __restrict__ xdbl)
{
    __shared__ float rows[XT][D_INNER];
    const int t0 = blockIdx.x * XT;
    for (int i = threadIdx.x; i < XT * D_INNER; i += 256)
        rows[i >> 11][i & 2047] = xi[(size_t)(t0 + (i >> 11)) * D_INNER + (i & 2047)];
    __syncthreads();

    const int wave = threadIdx.x >> 6;
    const int lane = threadIdx.x & 63;
    for (int e = wave; e < NDBL; e += 4) {
        const float* wr = W_x + (size_t)e * D_INNER;
        float s0 = 0.f, s1 = 0.f, s2 = 0.f, s3 = 0.f;
        for (int i = lane; i < D_INNER; i += 64) {
            float w = wr[i];
            s0 = fmaf(rows[0][i], w, s0);
            s1 = fmaf(rows[1][i], w, s1);
            s2 = fmaf(rows[2][i], w, s2);
            s3 = fmaf(rows[3][i], w, s3);
        }
#pragma unroll
        for (int off = 32; off; off >>= 1) {
            s0 += __shfl_xor(s0, off);
            s1 += __shfl_xor(s1, off);
            s2 += __shfl_xor(s2, off);
            s3 += __shfl_xor(s3, off);
        }
        if (lane == 0) {
            const int slot = (e == 0 ? 0 : e + 3);
            xdbl[(size_t)(t0 + 0) * XROW + slot] = s0;
            xdbl[(size_t)(t0 + 1) * XROW + slot] = s1;
            xdbl[(size_t)(t0 + 2) * XROW + slot] = s2;
            xdbl[(size_t)(t0 + 3) * XROW + slot] = s3;
        }
    }
}

// ---------------------------------------------------------------------------
// Chunked scan pass 1: thread per (b, d, chunk); all 16 n-states in registers.
// ---------------------------------------------------------------------------
__launch_bounds__(256)
__global__ void scan_pass1(const float* __restrict__ xdbl,
                           const float* __restrict__ xi,
                           const float* __restrict__ W_dt,
                           const float* __restrict__ b_dt,
                           const float* __restrict__ A_log,
                           float* __restrict__ aprod,
                           float* __restrict__ hloc)
{
    const int d = blockIdx.x * 256 + threadIdx.x;
    const int c = blockIdx.y;
    const int b = blockIdx.z;

    float A[16];
    {
        const float4* ar = (const float4*)(A_log + (size_t)d * 16);
#pragma unroll
        for (int q = 0; q < 4; ++q) {
            float4 v = ar[q];
            A[q * 4 + 0] = -__expf(v.x);
            A[q * 4 + 1] = -__expf(v.y);
            A[q * 4 + 2] = -__expf(v.z);
            A[q * 4 + 3] = -__expf(v.w);
        }
    }
    const float wdt = W_dt[d], bdt = b_dt[d];

    const float* xd = xdbl + ((size_t)b * SEQ + c * CHUNK) * XROW;
    const float* xp = xi + ((size_t)b * SEQ + c * CHUNK) * D_INNER + d;

    float h[16], ap[16], Bv[16];
#pragma unroll
    for (int n = 0; n < 16; ++n) { h[n] = 0.f; ap[n] = 1.f; }

    for (int l = 0; l < CHUNK; ++l) {
        float raw = xd[0];
#pragma unroll
        for (int q = 0; q < 4; ++q) {
            float4 v = *(const float4*)(xd + 4 + q * 4);
            Bv[q * 4 + 0] = v.x; Bv[q * 4 + 1] = v.y;
            Bv[q * 4 + 2] = v.z; Bv[q * 4 + 3] = v.w;
        }
        float xv = xp[0];
        float dtv = softplus_fast(fmaf(raw, wdt, bdt));
        float dtx = dtv * xv;
#pragma unroll
        for (int n = 0; n < 16; ++n) {
            float e = __expf(dtv * A[n]);
            h[n]  = fmaf(e, h[n], Bv[n] * dtx);
            ap[n] *= e;
        }
        xd += XROW; xp += D_INNER;
    }

    size_t s = (((size_t)b * NCHUNK + c) * D_INNER + d) * 16;
#pragma unroll
    for (int q = 0; q < 4; ++q) {
        *(float4*)(aprod + s + q * 4) = make_float4(ap[q*4], ap[q*4+1], ap[q*4+2], ap[q*4+3]);
        *(float4*)(hloc  + s + q * 4) = make_float4(h[q*4],  h[q*4+1],  h[q*4+2],  h[q*4+3]);
    }
}

// ---------------------------------------------------------------------------
// Chunked scan combine: serial over NCHUNK summaries; h_start in-place.
// ---------------------------------------------------------------------------
__global__ void scan_combine(float* __restrict__ aprod,
                             const float* __restrict__ hloc)
{
    int idx = blockIdx.x * blockDim.x + threadIdx.x;  // b*32768 + d*16 + n
    int b  = idx >> 15;
    int dn = idx & 32767;
    float hs = 0.f;
#pragma unroll
    for (int c = 0; c < NCHUNK; ++c) {
        size_t s = (((size_t)b * NCHUNK + c) << 15) + dn;
        float ap = aprod[s];
        float hl = hloc[s];
        aprod[s] = hs;                 // h_start for this chunk
        hs = fmaf(ap, hs, hl);
    }
}

// ---------------------------------------------------------------------------
// Chunked scan pass 2: rescan from h_start; emit gated y in-place into xi.
// ---------------------------------------------------------------------------
__launch_bounds__(256)
__global__ void scan_pass2(const float* __restrict__ xdbl,
                           float* __restrict__ xi,
                           const float* __restrict__ xz,
                           const float* __restrict__ W_dt,
                           const float* __restrict__ b_dt,
                           const float* __restrict__ A_log,
                           const float* __restrict__ Dvec,
                           const float* __restrict__ hstart)
{
    const int d = blockIdx.x * 256 + threadIdx.x;
    const int c = blockIdx.y;
    const int b = blockIdx.z;

    float A[16];
    {
        const float4* ar = (const float4*)(A_log + (size_t)d * 16);
#pragma unroll
        for (int q = 0; q < 4; ++q) {
            float4 v = ar[q];
            A[q * 4 + 0] = -__expf(v.x);
            A[q * 4 + 1] = -__expf(v.y);
            A[q * 4 + 2] = -__expf(v.z);
            A[q * 4 + 3] = -__expf(v.w);
        }
    }
    const float wdt = W_dt[d], bdt = b_dt[d], Dd = Dvec[d];

    const float* xd = xdbl + ((size_t)b * SEQ + c * CHUNK) * XROW;
    float*       xp = xi + ((size_t)b * SEQ + c * CHUNK) * D_INNER + d;
    const float* zp = xz + ((size_t)b * SEQ + c * CHUNK) * NXZ + D_INNER + d;

    float h[16], Bv[16], Cv[16];
    {
        size_t s = (((size_t)b * NCHUNK + c) * D_INNER + d) * 16;
#pragma unroll
        for (int q = 0; q < 4; ++q) {
            float4 v = *(const float4*)(hstart + s + q * 4);
            h[q * 4 + 0] = v.x; h[q * 4 + 1] = v.y;
            h[q * 4 + 2] = v.z; h[q * 4 + 3] = v.w;
        }
    }

    for (int l = 0; l < CHUNK; ++l) {
        float raw = xd[0];
#pragma unroll
        for (int q = 0; q < 4; ++q) {
            float4 v = *(const float4*)(xd + 4 + q * 4);
            Bv[q * 4 + 0] = v.x; Bv[q * 4 + 1] = v.y;
            Bv[q * 4 + 2] = v.z; Bv[q * 4 + 3] = v.w;
            float4 w = *(const float4*)(xd + 20 + q * 4);
            Cv[q * 4 + 0] = w.x; Cv[q * 4 + 1] = w.y;
            Cv[q * 4 + 2] = w.z; Cv[q * 4 + 3] = w.w;
        }
        float xv = xp[0];
        float zv = zp[0];
        float dtv = softplus_fast(fmaf(raw, wdt, bdt));
        float dtx = dtv * xv;

        float p0 = 0.f, p1 = 0.f, p2 = 0.f, p3 = 0.f;
#pragma unroll
        for (int q = 0; q < 4; ++q) {
            float e0 = __expf(dtv * A[q*4+0]);
            float e1 = __expf(dtv * A[q*4+1]);
            float e2 = __expf(dtv * A[q*4+2]);
            float e3 = __expf(dtv * A[q*4+3]);
            h[q*4+0] = fmaf(e0, h[q*4+0], Bv[q*4+0] * dtx);
            h[q*4+1] = fmaf(e1, h[q*4+1], Bv[q*4+1] * dtx);
            h[q*4+2] = fmaf(e2, h[q*4+2], Bv[q*4+2] * dtx);
            h[q*4+3] = fmaf(e3, h[q*4+3], Bv[q*4+3] * dtx);
            p0 = fmaf(h[q*4+0], Cv[q*4+0], p0);
            p1 = fmaf(h[q*4+1], Cv[q*4+1], p1);
            p2 = fmaf(h[q*4+2], Cv[q*4+2], p2);
            p3 = fmaf(h[q*4+3], Cv[q*4+3], p3);
        }
        float y = (p0 + p1) + (p2 + p3) + Dd * xv;
        xp[0] = y * silu_fast(zv);

        xd += XROW; xp += D_INNER; zp += NXZ;
    }
}

// ---------------------------------------------------------------------------
extern "C" void kernel_launch(void* const* d_in, const int* in_sizes, int n_in,
                              void* d_out, int out_size, void* d_ws, size_t ws_size,
                              hipStream_t stream)
{
    (void)in_sizes; (void)n_in; (void)out_size; (void)ws_size;

    const float* x      = (const float*)d_in[0];
    const float* W_in   = (const float*)d_in[1];
    const float* conv_w = (const float*)d_in[2];
    const float* conv_b = (const float*)d_in[3];
    const float* W_x    = (const float*)d_in[4];
    const float* W_dt   = (const float*)d_in[5];
    const float* b_dt   = (const float*)d_in[6];
    const float* A_log  = (const float*)d_in[7];
    const float* Dvec   = (const float*)d_in[8];
    const float* W_out  = (const float*)d_in[9];
    float* out = (float*)d_out;

    // ---- workspace map ----
    float* xz   = (float*)d_ws;                    // 4096x4096 f32 (64MB)
    float* xi   = xz + (size_t)NTOK * NXZ;         // 4096x2048 f32 (32MB)
    float* xdbl = xi + (size_t)NTOK * D_INNER;     // 4096x40 f32 (padded)
    float* R    = xdbl + (size_t)NTOK * XROW;      // shared region

    // phase-1 occupants of R: hi/lo splits of x and W_in (33.5MB)
    short* x_hi   = (short*)R;
    short* x_lo   = x_hi + (size_t)NTOK * D_MODEL;
    short* Win_hi = x_lo + (size_t)NTOK * D_MODEL;
    short* Win_lo = Win_hi + (size_t)NXZ * D_MODEL;
    // phase-2 occupants of R: scan buffers (aprod doubles as hstart; 33.5MB)
    float* aprod  = R;
    float* hloc   = aprod + (size_t)BATCH * NCHUNK * D_INNER * 16;
    // phase-3 occupants of xz region (z consumed by pass2): y / W_out splits
    short* y_hi   = (short*)xz;
    short* y_lo   = y_hi + (size_t)NTOK * D_INNER;
    short* Wou_hi = y_lo + (size_t)NTOK * D_INNER;
    short* Wou_lo = Wou_hi + (size_t)D_MODEL * D_INNER;

    // 0) split x and W_in to bf16 hi/lo
    split_kernel<<<(NTOK * D_MODEL / 4 + 255) / 256, 256, 0, stream>>>(x, x_hi, x_lo, NTOK * D_MODEL / 4);
    split_kernel<<<(NXZ * D_MODEL / 4 + 255) / 256, 256, 0, stream>>>(W_in, Win_hi, Win_lo, NXZ * D_MODEL / 4);

    // 1) xz = x @ W_in^T   (M=4096, N=4096, K=1024)
    {
        dim3 grid(NXZ / 128, NTOK / 128);
        mfma_gemm_split<<<grid, 256, 0, stream>>>(x_hi, x_lo, Win_hi, Win_lo, xz, NTOK, NXZ, D_MODEL);
    }
    // 2) depthwise conv + SiLU -> xi
    {
        int total = NTOK * D_INNER;
        conv_silu_kernel<<<(total + 255) / 256, 256, 0, stream>>>(xz, conv_w, conv_b, xi);
    }
    // 3) x_dbl = xi @ W_x^T  (padded rows)
    xdbl_kernel<<<NTOK / XT, 256, 0, stream>>>(xi, W_x, xdbl);

    // 4) chunked selective scan (register-resident n-states)
    {
        dim3 grid(D_INNER / 256, NCHUNK, BATCH);
        scan_pass1<<<grid, 256, 0, stream>>>(xdbl, xi, W_dt, b_dt, A_log, aprod, hloc);
        scan_combine<<<(BATCH * D_INNER * 16) / 256, 256, 0, stream>>>(aprod, hloc);
        scan_pass2<<<grid, 256, 0, stream>>>(xdbl, xi, xz, W_dt, b_dt, A_log, Dvec, aprod);
    }
    // 5) split y (=xi) and W_out, then out = y @ W_out^T  (M=4096, N=1024, K=2048)
    split_kernel<<<(NTOK * D_INNER / 4 + 255) / 256, 256, 0, stream>>>(xi, y_hi, y_lo, NTOK * D_INNER / 4);
    split_kernel<<<(D_MODEL * D_INNER / 4 + 255) / 256, 256, 0, stream>>>(W_out, Wou_hi, Wou_lo, D_MODEL * D_INNER / 4);
    {
        dim3 grid(D_MODEL / 128, NTOK / 128);
        mfma_gemm_split<<<grid, 256, 0, stream>>>(y_hi, y_lo, Wou_hi, Wou_lo, out, NTOK, D_MODEL, D_INNER);
    }
}